// Round 11
// baseline (174.939 us; speedup 1.0000x reference)
//
#include <hip/hip_runtime.h>
#include <hip/hip_bf16.h>

typedef float f32x4 __attribute__((ext_vector_type(4)));
typedef short s16x8 __attribute__((ext_vector_type(8)));
typedef short s16x4 __attribute__((ext_vector_type(4)));
typedef unsigned short u16x4 __attribute__((ext_vector_type(4)));

__device__ __forceinline__ float bf2f(unsigned short u) {
    union { unsigned int i; float f; } x; x.i = ((unsigned int)u) << 16; return x.f;
}
__device__ __forceinline__ unsigned short f2bf(float f) {
    union { float f; unsigned int i; } x; x.f = f;
    unsigned int r = x.i + 0x7FFFu + ((x.i >> 16) & 1u);
    return (unsigned short)(r >> 16);
}
__device__ __forceinline__ float silu_fast(float v) {
    return v * __builtin_amdgcn_rcpf(1.f + __expf(-v));
}

#define GLDS16(gp, lp) __builtin_amdgcn_global_load_lds( \
    (const __attribute__((address_space(1))) unsigned int*)(gp), \
    (__attribute__((address_space(3))) unsigned int*)(lp), 16, 0, 0)

// ---------------------------------------------------------------------------
// Kernel 0: fused  (a) f32->bf16 convert of X/W/Wo   (b) time-bucketize
// ---------------------------------------------------------------------------
__global__ __launch_bounds__(256) void cvt_bucketize(
    const float* __restrict__ X, const float* __restrict__ W,
    const float* __restrict__ Wo, const int* __restrict__ TS,
    unsigned short* __restrict__ Xb, unsigned short* __restrict__ Wb,
    unsigned short* __restrict__ Wob, unsigned char* __restrict__ BK)
{
    const int tid = threadIdx.x;
    if (blockIdx.x < 8192) {
        int idx = blockIdx.x * 256 + tid;       // f32x4 chunk id, 2097152 total
        const float* src; unsigned short* dst; int off;
        if (idx < 1048576)       { src = X;  dst = Xb;  off = idx; }
        else if (idx < 1835008)  { src = W;  dst = Wb;  off = idx - 1048576; }
        else                     { src = Wo; dst = Wob; off = idx - 1835008; }
        f32x4 v = *reinterpret_cast<const f32x4*>(&src[(size_t)off * 4]);
        u16x4 o;
        #pragma unroll
        for (int j = 0; j < 4; ++j) o[j] = f2bf(v[j]);
        *reinterpret_cast<u16x4*>(&dst[(size_t)off * 4]) = o;
        return;
    }
    const int bid = blockIdx.x - 8192;          // 0..2047
    const int jt = bid & 31, it = (bid >> 5) & 31, b = bid >> 10;
    if (jt > it) return;                        // causal only
    __shared__ int bndRaw[63];
    __shared__ int bnd[64];
    __shared__ int tsi[64], tsj[64];
    if (tid < 63) {
        double step = log(7776000.0) / 62.0;    // MAX_SPAN = 86400*90
        double v = exp(step * (double)tid);
        if (v < 1.0) v = 1.0;
        bndRaw[tid] = (int)floor(v);
    }
    if (tid >= 64 && tid < 128) tsi[tid - 64] = TS[b * 2048 + it * 64 + (tid - 64)];
    else if (tid >= 128 && tid < 192) tsj[tid - 128] = TS[b * 2048 + jt * 64 + (tid - 128)];
    __syncthreads();
    if (tid == 0) {                             // unique()
        int c = 0, p = -1;
        for (int i = 0; i < 63; ++i) { int x = bndRaw[i]; if (x != p) { bnd[c++] = x; p = x; } }
        for (; c < 64; ++c) bnd[c] = 0x7FFFFFFF;
    }
    __syncthreads();
    const int il = tid & 63, jc = (tid >> 6) * 16;
    const int tiv = tsi[il];
    unsigned char out[16];
    #pragma unroll
    for (int u = 0; u < 16; ++u) {
        int td = tiv - tsj[jc + u]; td = td < 0 ? -td : td; if (td < 1) td = 1;
        int pos = 0;
        #pragma unroll
        for (int st = 32; st; st >>= 1)
            if (bnd[pos + st - 1] < td) pos += st;
        out[u] = (unsigned char)pos;
    }
    *reinterpret_cast<int4*>(&BK[((size_t)b << 22) + (size_t)(it * 64 + il) * 2048 + jt * 64 + jc]) =
        *reinterpret_cast<const int4*>(out);
}

// ---------------------------------------------------------------------------
// Kernel 2: h = silu(Xb @ Wb^T + b); route into U, Vt, Q(*scale), K
// (frozen at R10: BK=64 swizzled LDS, single-buffer, 768 blocks)
// ---------------------------------------------------------------------------
__global__ __launch_bounds__(256) void gemm_uvqk(
    const unsigned short* __restrict__ Xb, const unsigned short* __restrict__ Wb,
    const float* __restrict__ bias,
    unsigned short* __restrict__ U, unsigned short* __restrict__ Vt,
    unsigned short* __restrict__ Q, unsigned short* __restrict__ K)
{
    __shared__ __align__(16) unsigned short sA[128][64];   // 16 KiB
    __shared__ __align__(16) unsigned short sB[128][64];   // 16 KiB
    const int tid = threadIdx.x;
    const int wv = tid >> 6, lane = tid & 63;
    const int g = lane >> 4, lr = lane & 15;
    const int wid = (blockIdx.x & 7) * 96 + (blockIdx.x >> 3);   // 768 blocks
    const int m0 = (wid & 31) * 128, n0 = (wid >> 5) * 128;
    const int wr = (wv >> 1) * 64, wc = (wv & 1) * 64;
    const int ls = lr & 7;
    f32x4 acc[4][4] = {};

    for (int k0 = 0; k0 < 1024; k0 += 64) {
        #pragma unroll
        for (int c = 0; c < 4; ++c) {
            int id = c * 256 + tid;
            int row = id >> 3, c8 = id & 7;
            int sc = (c8 ^ (row & 7)) * 8;      // pre-swizzled source column
            GLDS16(&Xb[(size_t)(m0 + row) * 1024 + k0 + sc], &sA[row][c8 * 8]);
            GLDS16(&Wb[(size_t)(n0 + row) * 1024 + k0 + sc], &sB[row][c8 * 8]);
        }
        __syncthreads();
        #pragma unroll
        for (int kq = 0; kq < 2; ++kq) {
            s16x8 afr[4], bfr[4];
            #pragma unroll
            for (int i = 0; i < 4; ++i) {
                afr[i] = *reinterpret_cast<const s16x8*>(
                    &sA[wr + i * 16 + lr][((kq * 4 + g) ^ ls) * 8]);
                bfr[i] = *reinterpret_cast<const s16x8*>(
                    &sB[wc + i * 16 + lr][((kq * 4 + g) ^ ls) * 8]);
            }
            #pragma unroll
            for (int mi = 0; mi < 4; ++mi)
                #pragma unroll
                for (int ni = 0; ni < 4; ++ni)
                    acc[mi][ni] = __builtin_amdgcn_mfma_f32_16x16x32_bf16(
                        afr[mi], bfr[ni], acc[mi][ni], 0, 0, 0);
        }
        __syncthreads();
    }

    if (n0 >= 1024 && n0 < 2048) {
        const int head = (n0 - 1024) >> 7;
        unsigned short* sT = &sA[0][0] + wv * (32 * 72);    // 4 x 4.5 KB
        #pragma unroll
        for (int hh = 0; hh < 2; ++hh) {
            #pragma unroll
            for (int nn = 0; nn < 2; ++nn) {
                int ni = hh * 2 + nn;
                float bn = bias[n0 + wc + ni * 16 + lr];
                #pragma unroll
                for (int mi = 0; mi < 4; ++mi)
                    #pragma unroll
                    for (int r = 0; r < 4; ++r)
                        sT[(nn * 16 + lr) * 72 + mi * 16 + g * 4 + r] =
                            f2bf(silu_fast(acc[mi][ni][r] + bn));
            }
            #pragma unroll
            for (int c = 0; c < 4; ++c) {
                int id = c * 64 + lane;
                int row = id >> 3, ch = id & 7;
                s16x8 val = *reinterpret_cast<const s16x8*>(&sT[row * 72 + ch * 8]);
                int d = wc + hh * 32 + row;
                int mg = m0 + wr + ch * 8;
                int bb = mg >> 11, l = mg & 2047;
                *reinterpret_cast<s16x8*>(
                    &Vt[(((size_t)(bb * 8 + head) * 128 + d) << 11) + l]) = val;
            }
        }
    } else {
        #pragma unroll
        for (int ni = 0; ni < 4; ++ni) {
            int n = n0 + wc + ni * 16 + lr;
            float bn = bias[n];
            #pragma unroll
            for (int mi = 0; mi < 4; ++mi) {
                #pragma unroll
                for (int r = 0; r < 4; ++r) {
                    int m = m0 + wr + mi * 16 + g * 4 + r;
                    float v = silu_fast(acc[mi][ni][r] + bn);
                    int b = m >> 11, l = m & 2047;
                    if (n < 1024) {
                        U[(size_t)m * 1024 + n] = f2bf(v);
                    } else if (n < 2560) {
                        int dd = n - 2048, h = dd >> 6, d = dd & 63;
                        Q[((((size_t)(b * 8 + h) << 11) + l) << 6) + d] = f2bf(v * 0.125f);
                    } else {
                        int dd = n - 2560, h = dd >> 6, d = dd & 63;
                        K[((((size_t)(b * 8 + h) << 11) + l) << 6) + d] = f2bf(v);
                    }
                }
            }
        }
    }
}

// ---------------------------------------------------------------------------
// Kernel 3: pointwise-silu attention. KVBLK=32, LDS 48 KB -> 2-3 blocks/CU.
// 8 waves: rowgroup rg=wv&3, half=wv>>2 handles jt32 = 2p+half (no clamp).
// Bias: per-lane dword loads (counted in vmcnt) + ds_bpermute table lookup.
// Per phase per thread: 3 glds (K 1 + V 2) + 2 bias dwords -> vmcnt(5).
// ---------------------------------------------------------------------------
__global__ __launch_bounds__(512, 6) void attn(
    const unsigned short* __restrict__ Q, const unsigned short* __restrict__ K,
    const unsigned short* __restrict__ Vt, const unsigned char* __restrict__ BK,
    const float* __restrict__ TB, unsigned short* __restrict__ Y)
{
    __shared__ __align__(16) char smem[49152];
    // sK: [2 dbuf][2 half][32][64]bf16 at 0      (db*8192 + half*4096), rows 128 B
    // sV: [2 dbuf][2 half][128][32]bf16 at 16384 (+ db*16384 + half*8192), rows 64 B

    const int tid = threadIdx.x, wv = tid >> 6, lane = tid & 63;
    const int g = lane >> 4, lr = lane & 15;

    const int bid = blockIdx.x;
    const int xcd = bid & 7, kix = bid >> 3;       // kix 0..63
    const int bh = 2 * xcd + (kix & 1);            // XCD owns 2 heads
    const int ti = 31 - (kix >> 1);                // heavy 64-row i-tiles first
    const int b = bh >> 3, h = bh & 7;
    const int i0 = ti * 64;
    const int rg = wv & 3;                         // rowgroup (16 rows)
    const int half = wv >> 2;                      // jt32 parity
    const int irow = i0 + rg * 16;
    const int P = ti + 1;                          // phases; phase p: jt32 = 2p+half

    const int tbl = __float_as_int(TB[lane * 8 + h]);   // tb table in registers

    const unsigned short* qb = Q + ((size_t)bh << 11) * 64;
    const unsigned short* kb = K + ((size_t)bh << 11) * 64;
    const unsigned short* vtb = Vt + ((size_t)bh << 7) * 2048;
    const unsigned char* bkp = BK + ((size_t)b << 22) + (size_t)(irow + lr) * 2048 + g * 4;

    s16x8 aq[2];
    #pragma unroll
    for (int kq = 0; kq < 2; ++kq)
        aq[kq] = *reinterpret_cast<const s16x8*>(&qb[(size_t)(irow + lr) * 64 + kq * 32 + g * 8]);

    char* base = smem;
    const int cs = lr & 7;
    const int ib = irow + lr;

    // stage this half's jt32 = 2p+half: K 1 chunk + V 2 chunks per thread
    auto stage = [&](int p, int db) {
        const int jt = 2 * p + half;               // always <= 2*ti+1, valid
        const size_t j0 = (size_t)jt * 32;
        char* kd = base + db * 8192 + half * 4096;
        char* vd = base + 16384 + db * 16384 + half * 8192;
        {
            int id = (rg << 6) | lane;             // 0..255 within half
            int row = id >> 3, c8 = id & 7;
            GLDS16(kb + (j0 + row) * 64 + ((c8 ^ (row & 7)) * 8), kd + id * 16);
        }
        #pragma unroll
        for (int c = 0; c < 2; ++c) {
            int id = c * 256 + ((rg << 6) | lane);
            int d = id >> 2, c16 = id & 3;
            GLDS16(vtb + (size_t)d * 2048 + j0 + ((c16 ^ (d & 3)) * 8), vd + id * 16);
        }
    };

#define BIAS_LOAD(p, bw) { const unsigned char* p_ = bkp + (size_t)(2 * (p) + half) * 32; \
        bw[0] = *(const unsigned int*)(p_); bw[1] = *(const unsigned int*)(p_ + 16); }

    f32x4 accy[8] = {};

#define COMPUTE(DB, BW, p) { \
        const int jt = 2 * (p) + half; \
        const char* kbase = base + (DB) * 8192 + half * 4096; \
        f32x4 sacc[2] = {}; \
        _Pragma("unroll") \
        for (int ni = 0; ni < 2; ++ni) { \
            _Pragma("unroll") \
            for (int kq = 0; kq < 2; ++kq) { \
                s16x8 kf = *reinterpret_cast<const s16x8*>( \
                    kbase + (ni * 16 + lr) * 128 + (((kq * 4 + g) ^ cs) << 4)); \
                sacc[ni] = __builtin_amdgcn_mfma_f32_16x16x32_bf16(kf, aq[kq], sacc[ni], 0, 0, 0); \
            } \
        } \
        const int j0 = jt * 32; \
        const bool diag = ((p) == P - 1); \
        s16x4 pf[2]; \
        _Pragma("unroll") \
        for (int ni = 0; ni < 2; ++ni) { \
            unsigned int bw = BW[ni]; \
            float b0 = __int_as_float(__builtin_amdgcn_ds_bpermute((int)((bw & 255u) << 2), tbl)); \
            float b1 = __int_as_float(__builtin_amdgcn_ds_bpermute((int)(((bw >> 8) & 255u) << 2), tbl)); \
            float b2 = __int_as_float(__builtin_amdgcn_ds_bpermute((int)(((bw >> 16) & 255u) << 2), tbl)); \
            float b3 = __int_as_float(__builtin_amdgcn_ds_bpermute((int)((bw >> 24) << 2), tbl)); \
            float v0 = silu_fast(sacc[ni][0] + b0); \
            float v1 = silu_fast(sacc[ni][1] + b1); \
            float v2 = silu_fast(sacc[ni][2] + b2); \
            float v3 = silu_fast(sacc[ni][3] + b3); \
            if (diag) { \
                int jb = j0 + ni * 16 + g * 4; \
                if (jb + 0 > ib) v0 = 0.f; \
                if (jb + 1 > ib) v1 = 0.f; \
                if (jb + 2 > ib) v2 = 0.f; \
                if (jb + 3 > ib) v3 = 0.f; \
            } \
            unsigned int w0, w1; \
            asm("v_cvt_pk_bf16_f32 %0, %1, %2" : "=v"(w0) : "v"(v0), "v"(v1)); \
            asm("v_cvt_pk_bf16_f32 %0, %1, %2" : "=v"(w1) : "v"(v2), "v"(v3)); \
            union { unsigned int u_[2]; s16x4 v_; } cvt_; \
            cvt_.u_[0] = w0; cvt_.u_[1] = w1; \
            pf[ni] = cvt_.v_; \
        } \
        const char* vbase = base + 16384 + (DB) * 16384 + half * 8192; \
        _Pragma("unroll") \
        for (int di = 0; di < 8; ++di) { \
            _Pragma("unroll") \
            for (int ni = 0; ni < 2; ++ni) { \
                s16x4 vf = *reinterpret_cast<const s16x4*>( \
                    vbase + (di * 16 + lr) * 64 + (((ni * 2 + (g >> 1)) ^ (lr & 3)) << 4) + ((g & 1) << 3)); \
                accy[di] = __builtin_amdgcn_mfma_f32_16x16x16bf16_1k(pf[ni], vf, accy[di], 0, 0, 0); \
            } \
        } }

    unsigned int bwA[2], bwB[2];
    stage(0, 0);
    BIAS_LOAD(0, bwA);

    int p = 0;
    for (;;) {
        __builtin_amdgcn_s_barrier();              // buf db^1 fully consumed
        if (p + 1 < P) {
            stage(p + 1, 1);
            BIAS_LOAD(p + 1, bwB);
            asm volatile("s_waitcnt vmcnt(5)" ::: "memory");   // phase p data landed
        } else {
            asm volatile("s_waitcnt vmcnt(0)" ::: "memory");
        }
        __builtin_amdgcn_s_barrier();              // all waves see phase p
        COMPUTE(0, bwA, p);
        if (++p == P) break;
        __builtin_amdgcn_s_barrier();
        if (p + 1 < P) {
            stage(p + 1, 0);
            BIAS_LOAD(p + 1, bwA);
            asm volatile("s_waitcnt vmcnt(5)" ::: "memory");
        } else {
            asm volatile("s_waitcnt vmcnt(0)" ::: "memory");
        }
        __builtin_amdgcn_s_barrier();
        COMPUTE(1, bwB, p);
        if (++p == P) break;
    }
#undef COMPUTE
#undef BIAS_LOAD

    // merge odd-jt partials (waves 4-7) into even-jt partials (waves 0-3)
    __syncthreads();
    float* red = (float*)base;                     // [64][132] f32 = 33.8 KB
    if (wv >= 4) {
        #pragma unroll
        for (int di = 0; di < 8; ++di)
            #pragma unroll
            for (int r = 0; r < 4; ++r)
                red[(rg * 16 + g * 4 + r) * 132 + di * 16 + lr] = accy[di][r];
    }
    __syncthreads();
    if (wv < 4) {
        #pragma unroll
        for (int di = 0; di < 8; ++di)
            #pragma unroll
            for (int r = 0; r < 4; ++r) {
                float s = accy[di][r] + red[(rg * 16 + g * 4 + r) * 132 + di * 16 + lr];
                Y[(size_t)((b << 11) + irow + g * 4 + r) * 1024 + h * 128 + di * 16 + lr] = f2bf(s);
            }
    }
}

// ---------------------------------------------------------------------------
// Kernel 4: RMSNorm over HID=1024 then U-gate; Y bf16 in, bf16 YP out.
// ---------------------------------------------------------------------------
__global__ __launch_bounds__(256) void rmsnorm_gate(
    const unsigned short* __restrict__ Y, const unsigned short* __restrict__ U,
    const float* __restrict__ rw, unsigned short* __restrict__ YP)
{
    __shared__ float red[4];
    const int row = blockIdx.x, tid = threadIdx.x;
    u16x4 v4 = *reinterpret_cast<const u16x4*>(&Y[(size_t)row * 1024 + tid * 4]);
    float v[4];
    #pragma unroll
    for (int j = 0; j < 4; ++j) v[j] = bf2f(v4[j]);
    float ss = v[0] * v[0] + v[1] * v[1] + v[2] * v[2] + v[3] * v[3];
    #pragma unroll
    for (int off = 32; off; off >>= 1) ss += __shfl_down(ss, off);
    if ((tid & 63) == 0) red[tid >> 6] = ss;
    __syncthreads();
    float rms = rsqrtf((red[0] + red[1] + red[2] + red[3]) * (1.f / 1024.f) + 1e-6f);
    #pragma unroll
    for (int j = 0; j < 4; ++j) {
        int c = tid * 4 + j;
        float o = v[j] * rms * rw[c] * bf2f(U[(size_t)row * 1024 + c]);
        YP[(size_t)row * 1024 + c] = f2bf(o);
    }
}

// ---------------------------------------------------------------------------
// Kernel 5: OUT = YP @ Wob^T + b_o. (frozen at R10)
// ---------------------------------------------------------------------------
__global__ __launch_bounds__(512) void gemm_out(
    const unsigned short* __restrict__ YP, const unsigned short* __restrict__ Wob,
    const float* __restrict__ bo, float* __restrict__ OUT)
{
    __shared__ __align__(16) unsigned short sA[128][64];
    __shared__ __align__(16) unsigned short sB[128][64];
    const int tid = threadIdx.x;
    const int wv = tid >> 6, lane = tid & 63;
    const int g = lane >> 4, lr = lane & 15;
    const int wid = (blockIdx.x & 7) * 32 + (blockIdx.x >> 3);   // 256 blocks
    const int m0 = (wid & 31) * 128, n0 = (wid >> 5) * 128;
    const int wr = (wv >> 2) * 64, wc = (wv & 3) * 32;
    const int ls = lr & 7;
    f32x4 acc[4][2] = {};

    for (int k0 = 0; k0 < 1024; k0 += 64) {
        #pragma unroll
        for (int c = 0; c < 2; ++c) {
            int id = c * 512 + tid;
            int row = id >> 3, c8 = id & 7;
            int sc = (c8 ^ (row & 7)) * 8;
            GLDS16(&YP[(size_t)(m0 + row) * 1024 + k0 + sc], &sA[row][c8 * 8]);
            GLDS16(&Wob[(size_t)(n0 + row) * 1024 + k0 + sc], &sB[row][c8 * 8]);
        }
        __syncthreads();
        #pragma unroll
        for (int kq = 0; kq < 2; ++kq) {
            s16x8 afr[4], bfr[2];
            #pragma unroll
            for (int i = 0; i < 4; ++i)
                afr[i] = *reinterpret_cast<const s16x8*>(
                    &sA[wr + i * 16 + lr][((kq * 4 + g) ^ ls) * 8]);
            #pragma unroll
            for (int i = 0; i < 2; ++i)
                bfr[i] = *reinterpret_cast<const s16x8*>(
                    &sB[wc + i * 16 + lr][((kq * 4 + g) ^ ls) * 8]);
            #pragma unroll
            for (int mi = 0; mi < 4; ++mi)
                #pragma unroll
                for (int ni = 0; ni < 2; ++ni)
                    acc[mi][ni] = __builtin_amdgcn_mfma_f32_16x16x32_bf16(
                        afr[mi], bfr[ni], acc[mi][ni], 0, 0, 0);
        }
        __syncthreads();
    }

    #pragma unroll
    for (int ni = 0; ni < 2; ++ni) {
        int n = n0 + wc + ni * 16 + lr;
        float bn = bo[n];
        #pragma unroll
        for (int mi = 0; mi < 4; ++mi)
            #pragma unroll
            for (int r = 0; r < 4; ++r) {
                int m = m0 + wr + mi * 16 + g * 4 + r;
                OUT[(size_t)m * 1024 + n] = acc[mi][ni][r] + bn;
            }
    }
}

// ---------------------------------------------------------------------------
extern "C" void kernel_launch(void* const* d_in, const int* in_sizes, int n_in,
                              void* d_out, int out_size, void* d_ws, size_t ws_size,
                              hipStream_t stream) {
    const float* X     = (const float*)d_in[0];
    const int*   TS    = (const int*)d_in[1];
    // d_in[2] = attn_mask (causal) — recomputed on device
    const float* Wuvqk = (const float*)d_in[3];
    const float* buvqk = (const float*)d_in[4];
    const float* TB    = (const float*)d_in[5];
    const float* Wo    = (const float*)d_in[6];
    const float* bo    = (const float*)d_in[7];
    const float* rw    = (const float*)d_in[8];
    float* OUT = (float*)d_out;

    char* ws = (char*)d_ws;
    unsigned short* Qb  = (unsigned short*)(ws);               //  4 MiB [2][8][2048][64]
    unsigned short* Kb  = (unsigned short*)(ws + (4u << 20));  //  4 MiB
    unsigned short* Vt  = (unsigned short*)(ws + (8u << 20));  //  8 MiB [2][8][128][2048]
    unsigned short* Ub  = (unsigned short*)(ws + (16u << 20)); //  8 MiB [4096][1024]
    unsigned short* Yb  = (unsigned short*)(ws + (24u << 20)); //  8 MiB bf16 (aliases Xb)
    unsigned short* Xb  = (unsigned short*)(ws + (24u << 20)); //  8 MiB
    unsigned short* Wb  = (unsigned short*)(ws + (32u << 20)); //  6 MiB
    unsigned short* YP  = (unsigned short*)(ws + (40u << 20)); //  8 MiB [4096][1024]
    unsigned char*  BKm = (unsigned char*)(ws + (48u << 20));  //  8 MiB [2][2048][2048]
    unsigned short* Wob = (unsigned short*)(ws + (56u << 20)); //  2 MiB [1024][1024]

    cvt_bucketize<<<10240, 256, 0, stream>>>(X, Wuvqk, Wo, TS, Xb, Wb, Wob, BKm);
    gemm_uvqk<<<768, 256, 0, stream>>>(Xb, Wb, buvqk, Ub, Vt, Qb, Kb);
    attn<<<512, 512, 0, stream>>>(Qb, Kb, Vt, BKm, TB, Yb);
    rmsnorm_gate<<<4096, 256, 0, stream>>>(Yb, Ub, rw, YP);
    gemm_out<<<256, 512, 0, stream>>>(YP, Wob, bo, OUT);
}

// Round 12
// 166.908 us; speedup vs baseline: 1.0481x; 1.0481x over previous
//
#include <hip/hip_runtime.h>
#include <hip/hip_bf16.h>

typedef float f32x4 __attribute__((ext_vector_type(4)));
typedef short s16x8 __attribute__((ext_vector_type(8)));
typedef short s16x4 __attribute__((ext_vector_type(4)));
typedef unsigned short u16x4 __attribute__((ext_vector_type(4)));

__device__ __forceinline__ float bf2f(unsigned short u) {
    union { unsigned int i; float f; } x; x.i = ((unsigned int)u) << 16; return x.f;
}
__device__ __forceinline__ unsigned short f2bf(float f) {
    union { float f; unsigned int i; } x; x.f = f;
    unsigned int r = x.i + 0x7FFFu + ((x.i >> 16) & 1u);
    return (unsigned short)(r >> 16);
}
__device__ __forceinline__ float silu_fast(float v) {
    return v * __builtin_amdgcn_rcpf(1.f + __expf(-v));
}

#define GLDS16(gp, lp) __builtin_amdgcn_global_load_lds( \
    (const __attribute__((address_space(1))) unsigned int*)(gp), \
    (__attribute__((address_space(3))) unsigned int*)(lp), 16, 0, 0)

// ---------------------------------------------------------------------------
// Kernel 0: fused  (a) f32->bf16 convert of X/W/Wo   (b) time-bucketize
// ---------------------------------------------------------------------------
__global__ __launch_bounds__(256) void cvt_bucketize(
    const float* __restrict__ X, const float* __restrict__ W,
    const float* __restrict__ Wo, const int* __restrict__ TS,
    unsigned short* __restrict__ Xb, unsigned short* __restrict__ Wb,
    unsigned short* __restrict__ Wob, unsigned char* __restrict__ BK)
{
    const int tid = threadIdx.x;
    if (blockIdx.x < 8192) {
        int idx = blockIdx.x * 256 + tid;       // f32x4 chunk id, 2097152 total
        const float* src; unsigned short* dst; int off;
        if (idx < 1048576)       { src = X;  dst = Xb;  off = idx; }
        else if (idx < 1835008)  { src = W;  dst = Wb;  off = idx - 1048576; }
        else                     { src = Wo; dst = Wob; off = idx - 1835008; }
        f32x4 v = *reinterpret_cast<const f32x4*>(&src[(size_t)off * 4]);
        u16x4 o;
        #pragma unroll
        for (int j = 0; j < 4; ++j) o[j] = f2bf(v[j]);
        *reinterpret_cast<u16x4*>(&dst[(size_t)off * 4]) = o;
        return;
    }
    const int bid = blockIdx.x - 8192;          // 0..2047
    const int jt = bid & 31, it = (bid >> 5) & 31, b = bid >> 10;
    if (jt > it) return;                        // causal only
    __shared__ int bndRaw[63];
    __shared__ int bnd[64];
    __shared__ int tsi[64], tsj[64];
    if (tid < 63) {
        double step = log(7776000.0) / 62.0;    // MAX_SPAN = 86400*90
        double v = exp(step * (double)tid);
        if (v < 1.0) v = 1.0;
        bndRaw[tid] = (int)floor(v);
    }
    if (tid >= 64 && tid < 128) tsi[tid - 64] = TS[b * 2048 + it * 64 + (tid - 64)];
    else if (tid >= 128 && tid < 192) tsj[tid - 128] = TS[b * 2048 + jt * 64 + (tid - 128)];
    __syncthreads();
    if (tid == 0) {                             // unique()
        int c = 0, p = -1;
        for (int i = 0; i < 63; ++i) { int x = bndRaw[i]; if (x != p) { bnd[c++] = x; p = x; } }
        for (; c < 64; ++c) bnd[c] = 0x7FFFFFFF;
    }
    __syncthreads();
    const int il = tid & 63, jc = (tid >> 6) * 16;
    const int tiv = tsi[il];
    unsigned char out[16];
    #pragma unroll
    for (int u = 0; u < 16; ++u) {
        int td = tiv - tsj[jc + u]; td = td < 0 ? -td : td; if (td < 1) td = 1;
        int pos = 0;
        #pragma unroll
        for (int st = 32; st; st >>= 1)
            if (bnd[pos + st - 1] < td) pos += st;
        out[u] = (unsigned char)pos;
    }
    *reinterpret_cast<int4*>(&BK[((size_t)b << 22) + (size_t)(it * 64 + il) * 2048 + jt * 64 + jc]) =
        *reinterpret_cast<const int4*>(out);
}

// ---------------------------------------------------------------------------
// Kernel 2: h = silu(Xb @ Wb^T + b); route into U, Vt, Q(*scale), K
// (frozen at R10: BK=64 swizzled LDS, single-buffer, 768 blocks)
// ---------------------------------------------------------------------------
__global__ __launch_bounds__(256) void gemm_uvqk(
    const unsigned short* __restrict__ Xb, const unsigned short* __restrict__ Wb,
    const float* __restrict__ bias,
    unsigned short* __restrict__ U, unsigned short* __restrict__ Vt,
    unsigned short* __restrict__ Q, unsigned short* __restrict__ K)
{
    __shared__ __align__(16) unsigned short sA[128][64];   // 16 KiB
    __shared__ __align__(16) unsigned short sB[128][64];   // 16 KiB
    const int tid = threadIdx.x;
    const int wv = tid >> 6, lane = tid & 63;
    const int g = lane >> 4, lr = lane & 15;
    const int wid = (blockIdx.x & 7) * 96 + (blockIdx.x >> 3);   // 768 blocks
    const int m0 = (wid & 31) * 128, n0 = (wid >> 5) * 128;
    const int wr = (wv >> 1) * 64, wc = (wv & 1) * 64;
    const int ls = lr & 7;
    f32x4 acc[4][4] = {};

    for (int k0 = 0; k0 < 1024; k0 += 64) {
        #pragma unroll
        for (int c = 0; c < 4; ++c) {
            int id = c * 256 + tid;
            int row = id >> 3, c8 = id & 7;
            int sc = (c8 ^ (row & 7)) * 8;      // pre-swizzled source column
            GLDS16(&Xb[(size_t)(m0 + row) * 1024 + k0 + sc], &sA[row][c8 * 8]);
            GLDS16(&Wb[(size_t)(n0 + row) * 1024 + k0 + sc], &sB[row][c8 * 8]);
        }
        __syncthreads();
        #pragma unroll
        for (int kq = 0; kq < 2; ++kq) {
            s16x8 afr[4], bfr[4];
            #pragma unroll
            for (int i = 0; i < 4; ++i) {
                afr[i] = *reinterpret_cast<const s16x8*>(
                    &sA[wr + i * 16 + lr][((kq * 4 + g) ^ ls) * 8]);
                bfr[i] = *reinterpret_cast<const s16x8*>(
                    &sB[wc + i * 16 + lr][((kq * 4 + g) ^ ls) * 8]);
            }
            #pragma unroll
            for (int mi = 0; mi < 4; ++mi)
                #pragma unroll
                for (int ni = 0; ni < 4; ++ni)
                    acc[mi][ni] = __builtin_amdgcn_mfma_f32_16x16x32_bf16(
                        afr[mi], bfr[ni], acc[mi][ni], 0, 0, 0);
        }
        __syncthreads();
    }

    if (n0 >= 1024 && n0 < 2048) {
        const int head = (n0 - 1024) >> 7;
        unsigned short* sT = &sA[0][0] + wv * (32 * 72);    // 4 x 4.5 KB
        #pragma unroll
        for (int hh = 0; hh < 2; ++hh) {
            #pragma unroll
            for (int nn = 0; nn < 2; ++nn) {
                int ni = hh * 2 + nn;
                float bn = bias[n0 + wc + ni * 16 + lr];
                #pragma unroll
                for (int mi = 0; mi < 4; ++mi)
                    #pragma unroll
                    for (int r = 0; r < 4; ++r)
                        sT[(nn * 16 + lr) * 72 + mi * 16 + g * 4 + r] =
                            f2bf(silu_fast(acc[mi][ni][r] + bn));
            }
            #pragma unroll
            for (int c = 0; c < 4; ++c) {
                int id = c * 64 + lane;
                int row = id >> 3, ch = id & 7;
                s16x8 val = *reinterpret_cast<const s16x8*>(&sT[row * 72 + ch * 8]);
                int d = wc + hh * 32 + row;
                int mg = m0 + wr + ch * 8;
                int bb = mg >> 11, l = mg & 2047;
                *reinterpret_cast<s16x8*>(
                    &Vt[(((size_t)(bb * 8 + head) * 128 + d) << 11) + l]) = val;
            }
        }
    } else {
        #pragma unroll
        for (int ni = 0; ni < 4; ++ni) {
            int n = n0 + wc + ni * 16 + lr;
            float bn = bias[n];
            #pragma unroll
            for (int mi = 0; mi < 4; ++mi) {
                #pragma unroll
                for (int r = 0; r < 4; ++r) {
                    int m = m0 + wr + mi * 16 + g * 4 + r;
                    float v = silu_fast(acc[mi][ni][r] + bn);
                    int b = m >> 11, l = m & 2047;
                    if (n < 1024) {
                        U[(size_t)m * 1024 + n] = f2bf(v);
                    } else if (n < 2560) {
                        int dd = n - 2048, h = dd >> 6, d = dd & 63;
                        Q[((((size_t)(b * 8 + h) << 11) + l) << 6) + d] = f2bf(v * 0.125f);
                    } else {
                        int dd = n - 2560, h = dd >> 6, d = dd & 63;
                        K[((((size_t)(b * 8 + h) << 11) + l) << 6) + d] = f2bf(v);
                    }
                }
            }
        }
    }
}

// ---------------------------------------------------------------------------
// Kernel 3: pointwise-silu attention. KVBLK=32 pairs, LDS 48 KB.
// sK [2db][2 half][32 j][64 d] (128-B rows); sV [2db][128 d][64 j] where
// j-cols 0-31 = even tile, 32-63 = odd tile (128-B rows -> conflict-free).
// All 8 waves stage jointly (per-lane global src picks the tile); waves
// 0-3 compute jt=2p, waves 4-7 jt=2p+1. Bias via register loads + bpermute.
// Per thread per stage: 3 glds + 2 bias dwords -> vmcnt(5).
// ---------------------------------------------------------------------------
__global__ __launch_bounds__(512, 4) void attn(
    const unsigned short* __restrict__ Q, const unsigned short* __restrict__ K,
    const unsigned short* __restrict__ Vt, const unsigned char* __restrict__ BK,
    const float* __restrict__ TB, unsigned short* __restrict__ Y)
{
    __shared__ __align__(16) char smem[49152];

    const int tid = threadIdx.x, wv = tid >> 6, lane = tid & 63;
    const int g = lane >> 4, lr = lane & 15;

    const int bid = blockIdx.x;
    const int xcd = bid & 7, kix = bid >> 3;       // kix 0..63
    const int bh = 2 * xcd + (kix & 1);            // XCD owns 2 heads
    const int ti = 31 - (kix >> 1);                // heavy 64-row i-tiles first
    const int b = bh >> 3, h = bh & 7;
    const int i0 = ti * 64;
    const int rg = wv & 3;                         // rowgroup (16 rows)
    const int half = wv >> 2;                      // jt parity this wave computes
    const int irow = i0 + rg * 16;
    const int P = ti + 1;                          // phases; phase p: jt = 2p+half

    const int tbl = __float_as_int(TB[lane * 8 + h]);   // tb table in registers

    const unsigned short* qb = Q + ((size_t)bh << 11) * 64;
    const unsigned short* kb = K + ((size_t)bh << 11) * 64;
    const unsigned short* vtb = Vt + ((size_t)bh << 7) * 2048;
    const unsigned char* bkp = BK + ((size_t)b << 22) + (size_t)(irow + lr) * 2048 + g * 4;

    s16x8 aq[2];
    #pragma unroll
    for (int kq = 0; kq < 2; ++kq)
        aq[kq] = *reinterpret_cast<const s16x8*>(&qb[(size_t)(irow + lr) * 64 + kq * 32 + g * 8]);

    char* base = smem;
    const int cs = lr & 7;
    const int ib = irow + lr;

    // joint staging of BOTH halves' tiles for phase p into dbuf db
    auto stage = [&](int p, int db) {
        const int j0e = p * 64;                    // = 2p*32, even tile base j
        char* kd = base + db * 8192;
        char* vd = base + 16384 + db * 16384;
        {   // K: 512 x 16B, dest [half][j][chunk], rows 128 B
            int r = tid >> 3, c8 = tid & 7;
            int jr = r & 31, hk = r >> 5;
            GLDS16(kb + (size_t)(j0e + hk * 32 + jr) * 64 + ((c8 ^ (jr & 7)) * 8),
                   kd + tid * 16);
        }
        #pragma unroll
        for (int c = 0; c < 2; ++c) {              // V: 1024 x 16B, dest [d][64 j]
            int id = c * 512 + tid;
            int d = id >> 3, L = id & 7;           // L: chunk in 128-B row
            int hv = L >> 2, c16 = L & 3;          // hv: which tile, c16: chunk in half
            GLDS16(vtb + (size_t)d * 2048 + j0e + hv * 32 + ((c16 ^ (d & 3)) * 8),
                   vd + id * 16);
        }
    };

#define BIAS_LOAD(p, bw) { const unsigned char* p_ = bkp + (size_t)(2 * (p) + half) * 32; \
        bw[0] = *(const unsigned int*)(p_); bw[1] = *(const unsigned int*)(p_ + 16); }

    f32x4 accy[8] = {};

#define COMPUTE(DB, BW, p) { \
        const int jt = 2 * (p) + half; \
        const char* kbase = base + (DB) * 8192 + half * 4096; \
        f32x4 sacc[2] = {}; \
        _Pragma("unroll") \
        for (int ni = 0; ni < 2; ++ni) { \
            _Pragma("unroll") \
            for (int kq = 0; kq < 2; ++kq) { \
                s16x8 kf = *reinterpret_cast<const s16x8*>( \
                    kbase + (ni * 16 + lr) * 128 + (((kq * 4 + g) ^ cs) << 4)); \
                sacc[ni] = __builtin_amdgcn_mfma_f32_16x16x32_bf16(kf, aq[kq], sacc[ni], 0, 0, 0); \
            } \
        } \
        const int j0 = jt * 32; \
        const bool diag = ((p) == P - 1); \
        s16x4 pf[2]; \
        _Pragma("unroll") \
        for (int ni = 0; ni < 2; ++ni) { \
            unsigned int bw = BW[ni]; \
            float b0 = __int_as_float(__builtin_amdgcn_ds_bpermute((int)((bw & 255u) << 2), tbl)); \
            float b1 = __int_as_float(__builtin_amdgcn_ds_bpermute((int)(((bw >> 8) & 255u) << 2), tbl)); \
            float b2 = __int_as_float(__builtin_amdgcn_ds_bpermute((int)(((bw >> 16) & 255u) << 2), tbl)); \
            float b3 = __int_as_float(__builtin_amdgcn_ds_bpermute((int)((bw >> 24) << 2), tbl)); \
            float v0 = silu_fast(sacc[ni][0] + b0); \
            float v1 = silu_fast(sacc[ni][1] + b1); \
            float v2 = silu_fast(sacc[ni][2] + b2); \
            float v3 = silu_fast(sacc[ni][3] + b3); \
            if (diag) { \
                int jb = j0 + ni * 16 + g * 4; \
                if (jb + 0 > ib) v0 = 0.f; \
                if (jb + 1 > ib) v1 = 0.f; \
                if (jb + 2 > ib) v2 = 0.f; \
                if (jb + 3 > ib) v3 = 0.f; \
            } \
            unsigned int w0, w1; \
            asm("v_cvt_pk_bf16_f32 %0, %1, %2" : "=v"(w0) : "v"(v0), "v"(v1)); \
            asm("v_cvt_pk_bf16_f32 %0, %1, %2" : "=v"(w1) : "v"(v2), "v"(v3)); \
            union { unsigned int u_[2]; s16x4 v_; } cvt_; \
            cvt_.u_[0] = w0; cvt_.u_[1] = w1; \
            pf[ni] = cvt_.v_; \
        } \
        const char* vbase = base + 16384 + (DB) * 16384 + half * 64; \
        _Pragma("unroll") \
        for (int di = 0; di < 8; ++di) { \
            _Pragma("unroll") \
            for (int ni = 0; ni < 2; ++ni) { \
                s16x4 vf = *reinterpret_cast<const s16x4*>( \
                    vbase + (di * 16 + lr) * 128 + ((((ni << 1) + (g >> 1)) ^ (lr & 3)) << 4) + ((g & 1) << 3)); \
                accy[di] = __builtin_amdgcn_mfma_f32_16x16x16bf16_1k(pf[ni], vf, accy[di], 0, 0, 0); \
            } \
        } }

    unsigned int bwA[2], bwB[2];
    stage(0, 0);
    BIAS_LOAD(0, bwA);

    int p = 0;
    for (;;) {
        __builtin_amdgcn_s_barrier();              // buf db^1 fully consumed
        if (p + 1 < P) {
            stage(p + 1, 1);
            BIAS_LOAD(p + 1, bwB);
            asm volatile("s_waitcnt vmcnt(5)" ::: "memory");   // phase p data landed
        } else {
            asm volatile("s_waitcnt vmcnt(0)" ::: "memory");
        }
        __builtin_amdgcn_s_barrier();              // all waves see phase p
        COMPUTE(0, bwA, p);
        if (++p == P) break;
        __builtin_amdgcn_s_barrier();
        if (p + 1 < P) {
            stage(p + 1, 0);
            BIAS_LOAD(p + 1, bwA);
            asm volatile("s_waitcnt vmcnt(5)" ::: "memory");
        } else {
            asm volatile("s_waitcnt vmcnt(0)" ::: "memory");
        }
        __builtin_amdgcn_s_barrier();
        COMPUTE(1, bwB, p);
        if (++p == P) break;
    }
#undef COMPUTE
#undef BIAS_LOAD

    // merge odd-jt partials (waves 4-7) into even-jt partials (waves 0-3)
    __syncthreads();
    float* red = (float*)base;                     // [64][132] f32 = 33.8 KB
    if (wv >= 4) {
        #pragma unroll
        for (int di = 0; di < 8; ++di)
            #pragma unroll
            for (int r = 0; r < 4; ++r)
                red[(rg * 16 + g * 4 + r) * 132 + di * 16 + lr] = accy[di][r];
    }
    __syncthreads();
    if (wv < 4) {
        #pragma unroll
        for (int di = 0; di < 8; ++di)
            #pragma unroll
            for (int r = 0; r < 4; ++r) {
                float s = accy[di][r] + red[(rg * 16 + g * 4 + r) * 132 + di * 16 + lr];
                Y[(size_t)((b << 11) + irow + g * 4 + r) * 1024 + h * 128 + di * 16 + lr] = f2bf(s);
            }
    }
}

// ---------------------------------------------------------------------------
// Kernel 4: RMSNorm over HID=1024 then U-gate; Y bf16 in, bf16 YP out.
// ---------------------------------------------------------------------------
__global__ __launch_bounds__(256) void rmsnorm_gate(
    const unsigned short* __restrict__ Y, const unsigned short* __restrict__ U,
    const float* __restrict__ rw, unsigned short* __restrict__ YP)
{
    __shared__ float red[4];
    const int row = blockIdx.x, tid = threadIdx.x;
    u16x4 v4 = *reinterpret_cast<const u16x4*>(&Y[(size_t)row * 1024 + tid * 4]);
    float v[4];
    #pragma unroll
    for (int j = 0; j < 4; ++j) v[j] = bf2f(v4[j]);
    float ss = v[0] * v[0] + v[1] * v[1] + v[2] * v[2] + v[3] * v[3];
    #pragma unroll
    for (int off = 32; off; off >>= 1) ss += __shfl_down(ss, off);
    if ((tid & 63) == 0) red[tid >> 6] = ss;
    __syncthreads();
    float rms = rsqrtf((red[0] + red[1] + red[2] + red[3]) * (1.f / 1024.f) + 1e-6f);
    #pragma unroll
    for (int j = 0; j < 4; ++j) {
        int c = tid * 4 + j;
        float o = v[j] * rms * rw[c] * bf2f(U[(size_t)row * 1024 + c]);
        YP[(size_t)row * 1024 + c] = f2bf(o);
    }
}

// ---------------------------------------------------------------------------
// Kernel 5: OUT = YP @ Wob^T + b_o. (frozen at R10)
// ---------------------------------------------------------------------------
__global__ __launch_bounds__(512) void gemm_out(
    const unsigned short* __restrict__ YP, const unsigned short* __restrict__ Wob,
    const float* __restrict__ bo, float* __restrict__ OUT)
{
    __shared__ __align__(16) unsigned short sA[128][64];
    __shared__ __align__(16) unsigned short sB[128][64];
    const int tid = threadIdx.x;
    const int wv = tid >> 6, lane = tid & 63;
    const int g = lane >> 4, lr = lane & 15;
    const int wid = (blockIdx.x & 7) * 32 + (blockIdx.x >> 3);   // 256 blocks
    const int m0 = (wid & 31) * 128, n0 = (wid >> 5) * 128;
    const int wr = (wv >> 2) * 64, wc = (wv & 3) * 32;
    const int ls = lr & 7;
    f32x4 acc[4][2] = {};

    for (int k0 = 0; k0 < 1024; k0 += 64) {
        #pragma unroll
        for (int c = 0; c < 2; ++c) {
            int id = c * 512 + tid;
            int row = id >> 3, c8 = id & 7;
            int sc = (c8 ^ (row & 7)) * 8;
            GLDS16(&YP[(size_t)(m0 + row) * 1024 + k0 + sc], &sA[row][c8 * 8]);
            GLDS16(&Wob[(size_t)(n0 + row) * 1024 + k0 + sc], &sB[row][c8 * 8]);
        }
        __syncthreads();
        #pragma unroll
        for (int kq = 0; kq < 2; ++kq) {
            s16x8 afr[4], bfr[2];
            #pragma unroll
            for (int i = 0; i < 4; ++i)
                afr[i] = *reinterpret_cast<const s16x8*>(
                    &sA[wr + i * 16 + lr][((kq * 4 + g) ^ ls) * 8]);
            #pragma unroll
            for (int i = 0; i < 2; ++i)
                bfr[i] = *reinterpret_cast<const s16x8*>(
                    &sB[wc + i * 16 + lr][((kq * 4 + g) ^ ls) * 8]);
            #pragma unroll
            for (int mi = 0; mi < 4; ++mi)
                #pragma unroll
                for (int ni = 0; ni < 2; ++ni)
                    acc[mi][ni] = __builtin_amdgcn_mfma_f32_16x16x32_bf16(
                        afr[mi], bfr[ni], acc[mi][ni], 0, 0, 0);
        }
        __syncthreads();
    }

    #pragma unroll
    for (int ni = 0; ni < 2; ++ni) {
        int n = n0 + wc + ni * 16 + lr;
        float bn = bo[n];
        #pragma unroll
        for (int mi = 0; mi < 4; ++mi)
            #pragma unroll
            for (int r = 0; r < 4; ++r) {
                int m = m0 + wr + mi * 16 + g * 4 + r;
                OUT[(size_t)m * 1024 + n] = acc[mi][ni][r] + bn;
            }
    }
}

// ---------------------------------------------------------------------------
extern "C" void kernel_launch(void* const* d_in, const int* in_sizes, int n_in,
                              void* d_out, int out_size, void* d_ws, size_t ws_size,
                              hipStream_t stream) {
    const float* X     = (const float*)d_in[0];
    const int*   TS    = (const int*)d_in[1];
    // d_in[2] = attn_mask (causal) — recomputed on device
    const float* Wuvqk = (const float*)d_in[3];
    const float* buvqk = (const float*)d_in[4];
    const float* TB    = (const float*)d_in[5];
    const float* Wo    = (const float*)d_in[6];
    const float* bo    = (const float*)d_in[7];
    const float* rw    = (const float*)d_in[8];
    float* OUT = (float*)d_out;

    char* ws = (char*)d_ws;
    unsigned short* Qb  = (unsigned short*)(ws);               //  4 MiB [2][8][2048][64]
    unsigned short* Kb  = (unsigned short*)(ws + (4u << 20));  //  4 MiB
    unsigned short* Vt  = (unsigned short*)(ws + (8u << 20));  //  8 MiB [2][8][128][2048]
    unsigned short* Ub  = (unsigned short*)(ws + (16u << 20)); //  8 MiB [4096][1024]
    unsigned short* Yb  = (unsigned short*)(ws + (24u << 20)); //  8 MiB bf16 (aliases Xb)
    unsigned short* Xb  = (unsigned short*)(ws + (24u << 20)); //  8 MiB
    unsigned short* Wb  = (unsigned short*)(ws + (32u << 20)); //  6 MiB
    unsigned short* YP  = (unsigned short*)(ws + (40u << 20)); //  8 MiB [4096][1024]
    unsigned char*  BKm = (unsigned char*)(ws + (48u << 20));  //  8 MiB [2][2048][2048]
    unsigned short* Wob = (unsigned short*)(ws + (56u << 20)); //  2 MiB [1024][1024]

    cvt_bucketize<<<10240, 256, 0, stream>>>(X, Wuvqk, Wo, TS, Xb, Wb, Wob, BKm);
    gemm_uvqk<<<768, 256, 0, stream>>>(Xb, Wb, buvqk, Ub, Vt, Qb, Kb);
    attn<<<512, 512, 0, stream>>>(Qb, Kb, Vt, BKm, TB, Yb);
    rmsnorm_gate<<<4096, 256, 0, stream>>>(Yb, Ub, rw, YP);
    gemm_out<<<256, 512, 0, stream>>>(YP, Wob, bo, OUT);
}

// Round 13
// 147.078 us; speedup vs baseline: 1.1894x; 1.1348x over previous
//
#include <hip/hip_runtime.h>
#include <hip/hip_bf16.h>

typedef float f32x4 __attribute__((ext_vector_type(4)));
typedef short s16x8 __attribute__((ext_vector_type(8)));
typedef short s16x4 __attribute__((ext_vector_type(4)));
typedef unsigned short u16x4 __attribute__((ext_vector_type(4)));

__device__ __forceinline__ float bf2f(unsigned short u) {
    union { unsigned int i; float f; } x; x.i = ((unsigned int)u) << 16; return x.f;
}
__device__ __forceinline__ unsigned short f2bf(float f) {
    union { float f; unsigned int i; } x; x.f = f;
    unsigned int r = x.i + 0x7FFFu + ((x.i >> 16) & 1u);
    return (unsigned short)(r >> 16);
}
__device__ __forceinline__ float silu_fast(float v) {
    return v * __builtin_amdgcn_rcpf(1.f + __expf(-v));
}

#define GLDS16(gp, lp) __builtin_amdgcn_global_load_lds( \
    (const __attribute__((address_space(1))) unsigned int*)(gp), \
    (__attribute__((address_space(3))) unsigned int*)(lp), 16, 0, 0)

// ---------------------------------------------------------------------------
// Kernel 0: fused  (a) f32->bf16 convert of X/W/Wo   (b) time-bucketize
// ---------------------------------------------------------------------------
__global__ __launch_bounds__(256) void cvt_bucketize(
    const float* __restrict__ X, const float* __restrict__ W,
    const float* __restrict__ Wo, const int* __restrict__ TS,
    unsigned short* __restrict__ Xb, unsigned short* __restrict__ Wb,
    unsigned short* __restrict__ Wob, unsigned char* __restrict__ BK)
{
    const int tid = threadIdx.x;
    if (blockIdx.x < 8192) {
        int idx = blockIdx.x * 256 + tid;       // f32x4 chunk id, 2097152 total
        const float* src; unsigned short* dst; int off;
        if (idx < 1048576)       { src = X;  dst = Xb;  off = idx; }
        else if (idx < 1835008)  { src = W;  dst = Wb;  off = idx - 1048576; }
        else                     { src = Wo; dst = Wob; off = idx - 1835008; }
        f32x4 v = *reinterpret_cast<const f32x4*>(&src[(size_t)off * 4]);
        u16x4 o;
        #pragma unroll
        for (int j = 0; j < 4; ++j) o[j] = f2bf(v[j]);
        *reinterpret_cast<u16x4*>(&dst[(size_t)off * 4]) = o;
        return;
    }
    const int bid = blockIdx.x - 8192;          // 0..2047
    const int jt = bid & 31, it = (bid >> 5) & 31, b = bid >> 10;
    if (jt > it) return;                        // causal only
    __shared__ int bndRaw[63];
    __shared__ int bnd[64];
    __shared__ int tsi[64], tsj[64];
    if (tid < 63) {
        double step = log(7776000.0) / 62.0;    // MAX_SPAN = 86400*90
        double v = exp(step * (double)tid);
        if (v < 1.0) v = 1.0;
        bndRaw[tid] = (int)floor(v);
    }
    if (tid >= 64 && tid < 128) tsi[tid - 64] = TS[b * 2048 + it * 64 + (tid - 64)];
    else if (tid >= 128 && tid < 192) tsj[tid - 128] = TS[b * 2048 + jt * 64 + (tid - 128)];
    __syncthreads();
    if (tid == 0) {                             // unique()
        int c = 0, p = -1;
        for (int i = 0; i < 63; ++i) { int x = bndRaw[i]; if (x != p) { bnd[c++] = x; p = x; } }
        for (; c < 64; ++c) bnd[c] = 0x7FFFFFFF;
    }
    __syncthreads();
    const int il = tid & 63, jc = (tid >> 6) * 16;
    const int tiv = tsi[il];
    unsigned char out[16];
    #pragma unroll
    for (int u = 0; u < 16; ++u) {
        int td = tiv - tsj[jc + u]; td = td < 0 ? -td : td; if (td < 1) td = 1;
        int pos = 0;
        #pragma unroll
        for (int st = 32; st; st >>= 1)
            if (bnd[pos + st - 1] < td) pos += st;
        out[u] = (unsigned char)pos;
    }
    *reinterpret_cast<int4*>(&BK[((size_t)b << 22) + (size_t)(it * 64 + il) * 2048 + jt * 64 + jc]) =
        *reinterpret_cast<const int4*>(out);
}

// ---------------------------------------------------------------------------
// Kernel 2: h = silu(Xb @ Wb^T + b); route into U, Vt, Q(*scale), K
// (frozen at R10: BK=64 swizzled LDS, single-buffer, 768 blocks)
// ---------------------------------------------------------------------------
__global__ __launch_bounds__(256) void gemm_uvqk(
    const unsigned short* __restrict__ Xb, const unsigned short* __restrict__ Wb,
    const float* __restrict__ bias,
    unsigned short* __restrict__ U, unsigned short* __restrict__ Vt,
    unsigned short* __restrict__ Q, unsigned short* __restrict__ K)
{
    __shared__ __align__(16) unsigned short sA[128][64];   // 16 KiB
    __shared__ __align__(16) unsigned short sB[128][64];   // 16 KiB
    const int tid = threadIdx.x;
    const int wv = tid >> 6, lane = tid & 63;
    const int g = lane >> 4, lr = lane & 15;
    const int wid = (blockIdx.x & 7) * 96 + (blockIdx.x >> 3);   // 768 blocks
    const int m0 = (wid & 31) * 128, n0 = (wid >> 5) * 128;
    const int wr = (wv >> 1) * 64, wc = (wv & 1) * 64;
    const int ls = lr & 7;
    f32x4 acc[4][4] = {};

    for (int k0 = 0; k0 < 1024; k0 += 64) {
        #pragma unroll
        for (int c = 0; c < 4; ++c) {
            int id = c * 256 + tid;
            int row = id >> 3, c8 = id & 7;
            int sc = (c8 ^ (row & 7)) * 8;      // pre-swizzled source column
            GLDS16(&Xb[(size_t)(m0 + row) * 1024 + k0 + sc], &sA[row][c8 * 8]);
            GLDS16(&Wb[(size_t)(n0 + row) * 1024 + k0 + sc], &sB[row][c8 * 8]);
        }
        __syncthreads();
        #pragma unroll
        for (int kq = 0; kq < 2; ++kq) {
            s16x8 afr[4], bfr[4];
            #pragma unroll
            for (int i = 0; i < 4; ++i) {
                afr[i] = *reinterpret_cast<const s16x8*>(
                    &sA[wr + i * 16 + lr][((kq * 4 + g) ^ ls) * 8]);
                bfr[i] = *reinterpret_cast<const s16x8*>(
                    &sB[wc + i * 16 + lr][((kq * 4 + g) ^ ls) * 8]);
            }
            #pragma unroll
            for (int mi = 0; mi < 4; ++mi)
                #pragma unroll
                for (int ni = 0; ni < 4; ++ni)
                    acc[mi][ni] = __builtin_amdgcn_mfma_f32_16x16x32_bf16(
                        afr[mi], bfr[ni], acc[mi][ni], 0, 0, 0);
        }
        __syncthreads();
    }

    if (n0 >= 1024 && n0 < 2048) {
        const int head = (n0 - 1024) >> 7;
        unsigned short* sT = &sA[0][0] + wv * (32 * 72);    // 4 x 4.5 KB
        #pragma unroll
        for (int hh = 0; hh < 2; ++hh) {
            #pragma unroll
            for (int nn = 0; nn < 2; ++nn) {
                int ni = hh * 2 + nn;
                float bn = bias[n0 + wc + ni * 16 + lr];
                #pragma unroll
                for (int mi = 0; mi < 4; ++mi)
                    #pragma unroll
                    for (int r = 0; r < 4; ++r)
                        sT[(nn * 16 + lr) * 72 + mi * 16 + g * 4 + r] =
                            f2bf(silu_fast(acc[mi][ni][r] + bn));
            }
            #pragma unroll
            for (int c = 0; c < 4; ++c) {
                int id = c * 64 + lane;
                int row = id >> 3, ch = id & 7;
                s16x8 val = *reinterpret_cast<const s16x8*>(&sT[row * 72 + ch * 8]);
                int d = wc + hh * 32 + row;
                int mg = m0 + wr + ch * 8;
                int bb = mg >> 11, l = mg & 2047;
                *reinterpret_cast<s16x8*>(
                    &Vt[(((size_t)(bb * 8 + head) * 128 + d) << 11) + l]) = val;
            }
        }
    } else {
        #pragma unroll
        for (int ni = 0; ni < 4; ++ni) {
            int n = n0 + wc + ni * 16 + lr;
            float bn = bias[n];
            #pragma unroll
            for (int mi = 0; mi < 4; ++mi) {
                #pragma unroll
                for (int r = 0; r < 4; ++r) {
                    int m = m0 + wr + mi * 16 + g * 4 + r;
                    float v = silu_fast(acc[mi][ni][r] + bn);
                    int b = m >> 11, l = m & 2047;
                    if (n < 1024) {
                        U[(size_t)m * 1024 + n] = f2bf(v);
                    } else if (n < 2560) {
                        int dd = n - 2048, h = dd >> 6, d = dd & 63;
                        Q[((((size_t)(b * 8 + h) << 11) + l) << 6) + d] = f2bf(v * 0.125f);
                    } else {
                        int dd = n - 2560, h = dd >> 6, d = dd & 63;
                        K[((((size_t)(b * 8 + h) << 11) + l) << 6) + d] = f2bf(v);
                    }
                }
            }
        }
    }
}

// ---------------------------------------------------------------------------
// Kernel 3: pointwise-silu attention.
// Block = 128-row i-super-tile (st) x j-half (jh). 8 waves own 16 rows each.
// One 64-j K/V tile staged per phase (R6's proven layouts/XOR patterns):
// sK [2db][64 j][64 d] 16 KB, sV [2db][128 d][64 j] 32 KB -> LDS 48 KB,
// 2-3 blocks/CU co-resident. jh=0: jt 0..st; jh=1: jt st+1..2st+1 (st+1
// phases each, balanced). Partial Y to Yb0/Yb1 (bf16), summed in rmsnorm.
// Bias via register dword loads + ds_bpermute table. vmcnt(7) prefetch.
// ---------------------------------------------------------------------------
__global__ __launch_bounds__(512, 4) void attn(
    const unsigned short* __restrict__ Q, const unsigned short* __restrict__ K,
    const unsigned short* __restrict__ Vt, const unsigned char* __restrict__ BK,
    const float* __restrict__ TB,
    unsigned short* __restrict__ Yb0, unsigned short* __restrict__ Yb1)
{
    __shared__ __align__(16) char smem[49152];
    // sK at 0     : [2 db][64 j][64 d] bf16, rows 128 B  (db*8192)
    // sV at 16384 : [2 db][128 d][64 j] bf16, rows 128 B (db*16384)

    const int tid = threadIdx.x, wv = tid >> 6, lane = tid & 63;
    const int g = lane >> 4, lr = lane & 15;

    const int bid = blockIdx.x;
    const int xcd = bid & 7, r_ = bid >> 3;        // r_ 0..63
    const int bh = 2 * xcd + (r_ & 1);             // XCD owns 2 heads
    const int k2 = r_ >> 1;                        // 0..31
    const int st = 15 - (k2 >> 1);                 // heavy super-tiles first
    const int jh = k2 & 1;                         // j-range half
    const int b = bh >> 3, h = bh & 7;
    const int i0 = st << 7;                        // 128-row super-tile base
    const int irow = i0 + wv * 16;                 // this wave's 16 rows
    const int jt0 = jh ? (st + 1) : 0;
    const int P = st + 1;                          // phases per block
    const int diagT = irow >> 6;                   // diagonal j-tile for this wave

    const int tbl = __float_as_int(TB[lane * 8 + h]);   // tb table in registers

    const unsigned short* qb = Q + ((size_t)bh << 11) * 64;
    const unsigned short* kb = K + ((size_t)bh << 11) * 64;
    const unsigned short* vtb = Vt + ((size_t)bh << 7) * 2048;
    const unsigned char* bkp = BK + ((size_t)b << 22) + (size_t)(irow + lr) * 2048 + g * 4;
    unsigned short* Yp = jh ? Yb1 : Yb0;

    s16x8 aq[2];
    #pragma unroll
    for (int kq = 0; kq < 2; ++kq)
        aq[kq] = *reinterpret_cast<const s16x8*>(&qb[(size_t)(irow + lr) * 64 + kq * 32 + g * 8]);

    char* base = smem;
    const int cs = lr & 7;
    const int ib = irow + lr;

    // stage one 64-j tile (K 8 KB + V 16 KB): 1 + 2 glds per thread
    auto stage = [&](int jt, int db) {
        const size_t j0 = (size_t)jt * 64;
        char* kd = base + db * 8192;
        char* vd = base + 16384 + db * 16384;
        {
            int row = tid >> 3, c8 = tid & 7;
            GLDS16(kb + (j0 + row) * 64 + ((c8 ^ (row & 7)) * 8), kd + tid * 16);
        }
        #pragma unroll
        for (int c = 0; c < 2; ++c) {
            int id = c * 512 + tid;
            int d = id >> 3, c8 = id & 7;
            GLDS16(vtb + (size_t)d * 2048 + j0 + ((c8 ^ (d & 7)) * 8), vd + id * 16);
        }
    };

#define BIAS_LOAD(jt, bw) { const unsigned char* p_ = bkp + (size_t)(jt) * 64; \
        bw[0] = *(const unsigned int*)(p_);      bw[1] = *(const unsigned int*)(p_ + 16); \
        bw[2] = *(const unsigned int*)(p_ + 32); bw[3] = *(const unsigned int*)(p_ + 48); }

    f32x4 accy[8] = {};

#define COMPUTE(DB, BW, jt) { \
        if ((jt) <= diagT) { \
            const char* kbase = base + (DB) * 8192; \
            f32x4 sacc[4] = {}; \
            _Pragma("unroll") \
            for (int ni = 0; ni < 4; ++ni) { \
                _Pragma("unroll") \
                for (int kq = 0; kq < 2; ++kq) { \
                    s16x8 kf = *reinterpret_cast<const s16x8*>( \
                        kbase + (ni * 16 + lr) * 128 + (((kq * 4 + g) ^ cs) << 4)); \
                    sacc[ni] = __builtin_amdgcn_mfma_f32_16x16x32_bf16(kf, aq[kq], sacc[ni], 0, 0, 0); \
                } \
            } \
            const int j0 = (jt) * 64; \
            const bool diag = ((jt) == diagT); \
            s16x4 pf[4]; \
            _Pragma("unroll") \
            for (int ni = 0; ni < 4; ++ni) { \
                unsigned int bw = BW[ni]; \
                float b0 = __int_as_float(__builtin_amdgcn_ds_bpermute((int)((bw & 255u) << 2), tbl)); \
                float b1 = __int_as_float(__builtin_amdgcn_ds_bpermute((int)(((bw >> 8) & 255u) << 2), tbl)); \
                float b2 = __int_as_float(__builtin_amdgcn_ds_bpermute((int)(((bw >> 16) & 255u) << 2), tbl)); \
                float b3 = __int_as_float(__builtin_amdgcn_ds_bpermute((int)((bw >> 24) << 2), tbl)); \
                float v0 = silu_fast(sacc[ni][0] + b0); \
                float v1 = silu_fast(sacc[ni][1] + b1); \
                float v2 = silu_fast(sacc[ni][2] + b2); \
                float v3 = silu_fast(sacc[ni][3] + b3); \
                if (diag) { \
                    int jb = j0 + ni * 16 + g * 4; \
                    if (jb + 0 > ib) v0 = 0.f; \
                    if (jb + 1 > ib) v1 = 0.f; \
                    if (jb + 2 > ib) v2 = 0.f; \
                    if (jb + 3 > ib) v3 = 0.f; \
                } \
                unsigned int w0, w1; \
                asm("v_cvt_pk_bf16_f32 %0, %1, %2" : "=v"(w0) : "v"(v0), "v"(v1)); \
                asm("v_cvt_pk_bf16_f32 %0, %1, %2" : "=v"(w1) : "v"(v2), "v"(v3)); \
                union { unsigned int u_[2]; s16x4 v_; } cvt_; \
                cvt_.u_[0] = w0; cvt_.u_[1] = w1; \
                pf[ni] = cvt_.v_; \
            } \
            const char* vbase = base + 16384 + (DB) * 16384; \
            _Pragma("unroll") \
            for (int di = 0; di < 8; ++di) { \
                _Pragma("unroll") \
                for (int ni = 0; ni < 4; ++ni) { \
                    s16x4 vf = *reinterpret_cast<const s16x4*>( \
                        vbase + (di * 16 + lr) * 128 + (((2 * ni + (g >> 1)) ^ cs) << 4) + ((g & 1) << 3)); \
                    accy[di] = __builtin_amdgcn_mfma_f32_16x16x16bf16_1k(pf[ni], vf, accy[di], 0, 0, 0); \
                } \
            } \
        } }

    unsigned int bwA[4], bwB[4];
    stage(jt0, 0);
    BIAS_LOAD(jt0, bwA);

    int p = 0;
    for (;;) {
        __builtin_amdgcn_s_barrier();              // buf db^1 fully consumed
        if (p + 1 < P) {
            stage(jt0 + p + 1, 1);
            BIAS_LOAD(jt0 + p + 1, bwB);
            asm volatile("s_waitcnt vmcnt(7)" ::: "memory");   // phase p data landed
        } else {
            asm volatile("s_waitcnt vmcnt(0)" ::: "memory");
        }
        __builtin_amdgcn_s_barrier();              // all waves see phase p
        COMPUTE(0, bwA, jt0 + p);
        if (++p == P) break;
        __builtin_amdgcn_s_barrier();
        if (p + 1 < P) {
            stage(jt0 + p + 1, 0);
            BIAS_LOAD(jt0 + p + 1, bwA);
            asm volatile("s_waitcnt vmcnt(7)" ::: "memory");
        } else {
            asm volatile("s_waitcnt vmcnt(0)" ::: "memory");
        }
        __builtin_amdgcn_s_barrier();
        COMPUTE(1, bwB, jt0 + p);
        if (++p == P) break;
    }
#undef COMPUTE
#undef BIAS_LOAD

    // each wave owns its rows outright: direct partial write, no merge
    #pragma unroll
    for (int di = 0; di < 8; ++di)
        #pragma unroll
        for (int r = 0; r < 4; ++r) {
            int i = irow + g * 4 + r;
            Yp[(size_t)((b << 11) + i) * 1024 + h * 128 + di * 16 + lr] = f2bf(accy[di][r]);
        }
}

// ---------------------------------------------------------------------------
// Kernel 4: RMSNorm over HID=1024 then U-gate; sums the two bf16 partials.
// ---------------------------------------------------------------------------
__global__ __launch_bounds__(256) void rmsnorm_gate(
    const unsigned short* __restrict__ Y0, const unsigned short* __restrict__ Y1,
    const unsigned short* __restrict__ U,
    const float* __restrict__ rw, unsigned short* __restrict__ YP)
{
    __shared__ float red[4];
    const int row = blockIdx.x, tid = threadIdx.x;
    u16x4 a4 = *reinterpret_cast<const u16x4*>(&Y0[(size_t)row * 1024 + tid * 4]);
    u16x4 b4 = *reinterpret_cast<const u16x4*>(&Y1[(size_t)row * 1024 + tid * 4]);
    float v[4];
    #pragma unroll
    for (int j = 0; j < 4; ++j) v[j] = bf2f(a4[j]) + bf2f(b4[j]);
    float ss = v[0] * v[0] + v[1] * v[1] + v[2] * v[2] + v[3] * v[3];
    #pragma unroll
    for (int off = 32; off; off >>= 1) ss += __shfl_down(ss, off);
    if ((tid & 63) == 0) red[tid >> 6] = ss;
    __syncthreads();
    float rms = rsqrtf((red[0] + red[1] + red[2] + red[3]) * (1.f / 1024.f) + 1e-6f);
    #pragma unroll
    for (int j = 0; j < 4; ++j) {
        int c = tid * 4 + j;
        float o = v[j] * rms * rw[c] * bf2f(U[(size_t)row * 1024 + c]);
        YP[(size_t)row * 1024 + c] = f2bf(o);
    }
}

// ---------------------------------------------------------------------------
// Kernel 5: OUT = YP @ Wob^T + b_o. (frozen at R10)
// ---------------------------------------------------------------------------
__global__ __launch_bounds__(512) void gemm_out(
    const unsigned short* __restrict__ YP, const unsigned short* __restrict__ Wob,
    const float* __restrict__ bo, float* __restrict__ OUT)
{
    __shared__ __align__(16) unsigned short sA[128][64];
    __shared__ __align__(16) unsigned short sB[128][64];
    const int tid = threadIdx.x;
    const int wv = tid >> 6, lane = tid & 63;
    const int g = lane >> 4, lr = lane & 15;
    const int wid = (blockIdx.x & 7) * 32 + (blockIdx.x >> 3);   // 256 blocks
    const int m0 = (wid & 31) * 128, n0 = (wid >> 5) * 128;
    const int wr = (wv >> 2) * 64, wc = (wv & 3) * 32;
    const int ls = lr & 7;
    f32x4 acc[4][2] = {};

    for (int k0 = 0; k0 < 1024; k0 += 64) {
        #pragma unroll
        for (int c = 0; c < 2; ++c) {
            int id = c * 512 + tid;
            int row = id >> 3, c8 = id & 7;
            int sc = (c8 ^ (row & 7)) * 8;
            GLDS16(&YP[(size_t)(m0 + row) * 1024 + k0 + sc], &sA[row][c8 * 8]);
            GLDS16(&Wob[(size_t)(n0 + row) * 1024 + k0 + sc], &sB[row][c8 * 8]);
        }
        __syncthreads();
        #pragma unroll
        for (int kq = 0; kq < 2; ++kq) {
            s16x8 afr[4], bfr[2];
            #pragma unroll
            for (int i = 0; i < 4; ++i)
                afr[i] = *reinterpret_cast<const s16x8*>(
                    &sA[wr + i * 16 + lr][((kq * 4 + g) ^ ls) * 8]);
            #pragma unroll
            for (int i = 0; i < 2; ++i)
                bfr[i] = *reinterpret_cast<const s16x8*>(
                    &sB[wc + i * 16 + lr][((kq * 4 + g) ^ ls) * 8]);
            #pragma unroll
            for (int mi = 0; mi < 4; ++mi)
                #pragma unroll
                for (int ni = 0; ni < 2; ++ni)
                    acc[mi][ni] = __builtin_amdgcn_mfma_f32_16x16x32_bf16(
                        afr[mi], bfr[ni], acc[mi][ni], 0, 0, 0);
        }
        __syncthreads();
    }

    #pragma unroll
    for (int ni = 0; ni < 2; ++ni) {
        int n = n0 + wc + ni * 16 + lr;
        float bn = bo[n];
        #pragma unroll
        for (int mi = 0; mi < 4; ++mi)
            #pragma unroll
            for (int r = 0; r < 4; ++r) {
                int m = m0 + wr + mi * 16 + g * 4 + r;
                OUT[(size_t)m * 1024 + n] = acc[mi][ni][r] + bn;
            }
    }
}

// ---------------------------------------------------------------------------
extern "C" void kernel_launch(void* const* d_in, const int* in_sizes, int n_in,
                              void* d_out, int out_size, void* d_ws, size_t ws_size,
                              hipStream_t stream) {
    const float* X     = (const float*)d_in[0];
    const int*   TS    = (const int*)d_in[1];
    // d_in[2] = attn_mask (causal) — recomputed on device
    const float* Wuvqk = (const float*)d_in[3];
    const float* buvqk = (const float*)d_in[4];
    const float* TB    = (const float*)d_in[5];
    const float* Wo    = (const float*)d_in[6];
    const float* bo    = (const float*)d_in[7];
    const float* rw    = (const float*)d_in[8];
    float* OUT = (float*)d_out;

    char* ws = (char*)d_ws;
    unsigned short* Qb  = (unsigned short*)(ws);               //  4 MiB [2][8][2048][64]
    unsigned short* Kb  = (unsigned short*)(ws + (4u << 20));  //  4 MiB
    unsigned short* Vt  = (unsigned short*)(ws + (8u << 20));  //  8 MiB [2][8][128][2048]
    unsigned short* Ub  = (unsigned short*)(ws + (16u << 20)); //  8 MiB [4096][1024]
    unsigned char*  BKm = (unsigned char*)(ws + (24u << 20));  //  8 MiB [2][2048][2048]
    unsigned short* Xb  = (unsigned short*)(ws + (32u << 20)); //  8 MiB (dead after gemm_uvqk)
    unsigned short* Wb  = (unsigned short*)(ws + (40u << 20)); //  6 MiB (dead after gemm_uvqk)
    unsigned short* Yb0 = (unsigned short*)(ws + (32u << 20)); //  8 MiB (aliases Xb)
    unsigned short* Yb1 = (unsigned short*)(ws + (40u << 20)); //  8 MiB (aliases Wb + 2 MiB free)
    unsigned short* Wob = (unsigned short*)(ws + (48u << 20)); //  2 MiB [1024][1024]
    unsigned short* YP  = (unsigned short*)(ws + (50u << 20)); //  8 MiB [4096][1024]

    cvt_bucketize<<<10240, 256, 0, stream>>>(X, Wuvqk, Wo, TS, Xb, Wb, Wob, BKm);
    gemm_uvqk<<<768, 256, 0, stream>>>(Xb, Wb, buvqk, Ub, Vt, Qb, Kb);
    attn<<<512, 512, 0, stream>>>(Qb, Kb, Vt, BKm, TB, Yb0, Yb1);
    rmsnorm_gate<<<4096, 256, 0, stream>>>(Yb0, Yb1, Ub, rw, YP);
    gemm_out<<<256, 512, 0, stream>>>(YP, Wob, bo, OUT);
}

// Round 14
// 133.940 us; speedup vs baseline: 1.3061x; 1.0981x over previous
//
#include <hip/hip_runtime.h>
#include <hip/hip_bf16.h>

typedef float f32x4 __attribute__((ext_vector_type(4)));
typedef short s16x8 __attribute__((ext_vector_type(8)));
typedef short s16x4 __attribute__((ext_vector_type(4)));
typedef unsigned short u16x4 __attribute__((ext_vector_type(4)));

__device__ __forceinline__ float bf2f(unsigned short u) {
    union { unsigned int i; float f; } x; x.i = ((unsigned int)u) << 16; return x.f;
}
__device__ __forceinline__ unsigned short f2bf(float f) {
    union { float f; unsigned int i; } x; x.f = f;
    unsigned int r = x.i + 0x7FFFu + ((x.i >> 16) & 1u);
    return (unsigned short)(r >> 16);
}
__device__ __forceinline__ float silu_fast(float v) {
    return v * __builtin_amdgcn_rcpf(1.f + __expf(-v));
}

#define GLDS16(gp, lp) __builtin_amdgcn_global_load_lds( \
    (const __attribute__((address_space(1))) unsigned int*)(gp), \
    (__attribute__((address_space(3))) unsigned int*)(lp), 16, 0, 0)

// ---------------------------------------------------------------------------
// Kernel 0: fused  (a) f32->bf16 convert of X/W/Wo   (b) time-bucketize
// ---------------------------------------------------------------------------
__global__ __launch_bounds__(256) void cvt_bucketize(
    const float* __restrict__ X, const float* __restrict__ W,
    const float* __restrict__ Wo, const int* __restrict__ TS,
    unsigned short* __restrict__ Xb, unsigned short* __restrict__ Wb,
    unsigned short* __restrict__ Wob, unsigned char* __restrict__ BK)
{
    const int tid = threadIdx.x;
    if (blockIdx.x < 8192) {
        int idx = blockIdx.x * 256 + tid;       // f32x4 chunk id, 2097152 total
        const float* src; unsigned short* dst; int off;
        if (idx < 1048576)       { src = X;  dst = Xb;  off = idx; }
        else if (idx < 1835008)  { src = W;  dst = Wb;  off = idx - 1048576; }
        else                     { src = Wo; dst = Wob; off = idx - 1835008; }
        f32x4 v = *reinterpret_cast<const f32x4*>(&src[(size_t)off * 4]);
        u16x4 o;
        #pragma unroll
        for (int j = 0; j < 4; ++j) o[j] = f2bf(v[j]);
        *reinterpret_cast<u16x4*>(&dst[(size_t)off * 4]) = o;
        return;
    }
    const int bid = blockIdx.x - 8192;          // 0..2047
    const int jt = bid & 31, it = (bid >> 5) & 31, b = bid >> 10;
    if (jt > it) return;                        // causal only
    __shared__ int bndRaw[63];
    __shared__ int bnd[64];
    __shared__ int tsi[64], tsj[64];
    if (tid < 63) {
        double step = log(7776000.0) / 62.0;    // MAX_SPAN = 86400*90
        double v = exp(step * (double)tid);
        if (v < 1.0) v = 1.0;
        bndRaw[tid] = (int)floor(v);
    }
    if (tid >= 64 && tid < 128) tsi[tid - 64] = TS[b * 2048 + it * 64 + (tid - 64)];
    else if (tid >= 128 && tid < 192) tsj[tid - 128] = TS[b * 2048 + jt * 64 + (tid - 128)];
    __syncthreads();
    if (tid == 0) {                             // unique()
        int c = 0, p = -1;
        for (int i = 0; i < 63; ++i) { int x = bndRaw[i]; if (x != p) { bnd[c++] = x; p = x; } }
        for (; c < 64; ++c) bnd[c] = 0x7FFFFFFF;
    }
    __syncthreads();
    const int il = tid & 63, jc = (tid >> 6) * 16;
    const int tiv = tsi[il];
    unsigned char out[16];
    #pragma unroll
    for (int u = 0; u < 16; ++u) {
        int td = tiv - tsj[jc + u]; td = td < 0 ? -td : td; if (td < 1) td = 1;
        int pos = 0;
        #pragma unroll
        for (int st = 32; st; st >>= 1)
            if (bnd[pos + st - 1] < td) pos += st;
        out[u] = (unsigned char)pos;
    }
    *reinterpret_cast<int4*>(&BK[((size_t)b << 22) + (size_t)(it * 64 + il) * 2048 + jt * 64 + jc]) =
        *reinterpret_cast<const int4*>(out);
}

// ---------------------------------------------------------------------------
// Kernel 2: h = silu(Xb @ Wb^T + b); route into U, Vt, Q(*scale), K
// 8-phase template: 256x256 tile, BK=64, 8 waves (2Mx4N), 128 KB LDS dbuf.
// Per K-tile: 4 phases {ds_read subtile | stage half-op | vmcnt(4)@ph0 |
// barrier | lgkm(0)+sched_barrier | setprio(1) 16 MFMA setprio(0) | barrier}.
// Counted vmcnt never drains in steady state (prefetch issued BEFORE wait).
// ---------------------------------------------------------------------------
__global__ __launch_bounds__(512, 2) void gemm_uvqk(
    const unsigned short* __restrict__ Xb, const unsigned short* __restrict__ Wb,
    const float* __restrict__ bias,
    unsigned short* __restrict__ U, unsigned short* __restrict__ Vt,
    unsigned short* __restrict__ Q, unsigned short* __restrict__ K)
{
    __shared__ __align__(16) unsigned short smem[2][2][256][64];   // 128 KiB
    const int tid = threadIdx.x;
    const int wv = tid >> 6, lane = tid & 63;
    const int g = lane >> 4, lr = lane & 15;
    const int wid = (blockIdx.x & 7) * 24 + (blockIdx.x >> 3);     // 192 blocks
    const int mt = wid & 15, nt = wid >> 4;
    const int m0 = mt * 256, n0 = nt * 256;
    const int wm = wv >> 2, wn = wv & 3;       // 2M x 4N wave grid
    const int ls = lr & 7;
    f32x4 acc[8][4] = {};

    // stage one 256x64 operand (32 KB, 4 x GLDS16/thread), XOR-preswizzled src
    auto stageA = [&](int kt, int db) {
        const int k0 = kt * 64;
        #pragma unroll
        for (int c = 0; c < 4; ++c) {
            int id = c * 512 + tid;
            int row = id >> 3, c8 = id & 7;
            GLDS16(&Xb[(size_t)(m0 + row) * 1024 + k0 + (c8 ^ (row & 7)) * 8],
                   &smem[db][0][row][c8 * 8]);
        }
    };
    auto stageB = [&](int kt, int db) {
        const int k0 = kt * 64;
        #pragma unroll
        for (int c = 0; c < 4; ++c) {
            int id = c * 512 + tid;
            int row = id >> 3, c8 = id & 7;
            GLDS16(&Wb[(size_t)(n0 + row) * 1024 + k0 + (c8 ^ (row & 7)) * 8],
                   &smem[db][1][row][c8 * 8]);
        }
    };

    stageB(0, 0); stageA(0, 0);                // prologue: K-tile 0

    for (int kt = 0; kt < 16; ++kt) {
        const int db = kt & 1;
        const unsigned short (*sA)[64] = smem[db][0];
        const unsigned short (*sB)[64] = smem[db][1];
        s16x8 bfr[4][2];
        #pragma unroll
        for (int q = 0; q < 4; ++q) {
            if (q == 0) {
                // prefetch next tile's B BEFORE the wait -> wait never drains
                if (kt < 15) {
                    stageB(kt + 1, db ^ 1);
                    asm volatile("s_waitcnt vmcnt(4)" ::: "memory");  // kt's 8 landed
                } else {
                    asm volatile("s_waitcnt vmcnt(0)" ::: "memory");
                }
                __builtin_amdgcn_s_barrier();  // all waves' kt loads visible
            }
            // ds_read this phase's fragments
            s16x8 afr[2][2];
            if (q == 0) {
                #pragma unroll
                for (int ni = 0; ni < 4; ++ni)
                    #pragma unroll
                    for (int kq = 0; kq < 2; ++kq)
                        bfr[ni][kq] = *reinterpret_cast<const s16x8*>(
                            &sB[wn * 64 + ni * 16 + lr][((kq * 4 + g) ^ ls) * 8]);
            }
            #pragma unroll
            for (int j = 0; j < 2; ++j)
                #pragma unroll
                for (int kq = 0; kq < 2; ++kq)
                    afr[j][kq] = *reinterpret_cast<const s16x8*>(
                        &sA[wm * 128 + (2 * q + j) * 16 + lr][((kq * 4 + g) ^ ls) * 8]);
            if (q == 1 && kt < 15) stageA(kt + 1, db ^ 1);
            asm volatile("s_waitcnt lgkmcnt(0)" ::: "memory");
            __builtin_amdgcn_sched_barrier(0);
            __builtin_amdgcn_s_setprio(1);
            #pragma unroll
            for (int kq = 0; kq < 2; ++kq)
                #pragma unroll
                for (int j = 0; j < 2; ++j)
                    #pragma unroll
                    for (int ni = 0; ni < 4; ++ni)
                        acc[2 * q + j][ni] = __builtin_amdgcn_mfma_f32_16x16x32_bf16(
                            afr[j][kq], bfr[ni][kq], acc[2 * q + j][ni], 0, 0, 0);
            __builtin_amdgcn_s_setprio(0);
            __builtin_amdgcn_s_barrier();
        }
    }
    __syncthreads();                            // LDS free for epilogue scratch

    if (n0 >= 1024 && n0 < 2048) {
        // V region: per-wave LDS transpose -> coalesced Vt stores.
        // Wave cols: dglob..dglob+63 (64-aligned -> single head).
        const int dglob = n0 - 1024 + wn * 64;
        const int head = dglob >> 7, dbase = dglob & 127;
        unsigned short* sT = &smem[0][0][0][0] + wv * 2304;   // 32x72 per wave
        #pragma unroll
        for (int mh = 0; mh < 2; ++mh) {
            #pragma unroll
            for (int hh = 0; hh < 2; ++hh) {
                #pragma unroll
                for (int nn = 0; nn < 2; ++nn) {
                    int ni = hh * 2 + nn;
                    float bn = bias[n0 + wn * 64 + ni * 16 + lr];
                    #pragma unroll
                    for (int mi = 0; mi < 4; ++mi)
                        #pragma unroll
                        for (int r = 0; r < 4; ++r)
                            sT[(nn * 16 + lr) * 72 + mi * 16 + g * 4 + r] =
                                f2bf(silu_fast(acc[mh * 4 + mi][ni][r] + bn));
                }
                #pragma unroll
                for (int c = 0; c < 4; ++c) {
                    int id = c * 64 + lane;
                    int row = id >> 3, ch = id & 7;
                    s16x8 val = *reinterpret_cast<const s16x8*>(&sT[row * 72 + ch * 8]);
                    int d = dbase + hh * 32 + row;
                    int mg = m0 + wm * 128 + mh * 64 + ch * 8;
                    int bb = mg >> 11, l = mg & 2047;
                    *reinterpret_cast<s16x8*>(
                        &Vt[(((size_t)(bb * 8 + head) * 128 + d) << 11) + l]) = val;
                }
            }
        }
    } else {
        #pragma unroll
        for (int ni = 0; ni < 4; ++ni) {
            int n = n0 + wn * 64 + ni * 16 + lr;
            float bn = bias[n];
            #pragma unroll
            for (int mi = 0; mi < 8; ++mi) {
                #pragma unroll
                for (int r = 0; r < 4; ++r) {
                    int m = m0 + wm * 128 + mi * 16 + g * 4 + r;
                    float v = silu_fast(acc[mi][ni][r] + bn);
                    int b = m >> 11, l = m & 2047;
                    if (n < 1024) {
                        U[(size_t)m * 1024 + n] = f2bf(v);
                    } else if (n < 2560) {
                        int dd = n - 2048, h = dd >> 6, d = dd & 63;
                        Q[((((size_t)(b * 8 + h) << 11) + l) << 6) + d] = f2bf(v * 0.125f);
                    } else {
                        int dd = n - 2560, h = dd >> 6, d = dd & 63;
                        K[((((size_t)(b * 8 + h) << 11) + l) << 6) + d] = f2bf(v);
                    }
                }
            }
        }
    }
}

// ---------------------------------------------------------------------------
// Kernel 3: pointwise-silu attention (R10 form — best-total config).
// ---------------------------------------------------------------------------
__global__ __launch_bounds__(512, 1) void attn(
    const unsigned short* __restrict__ Q, const unsigned short* __restrict__ K,
    const unsigned short* __restrict__ Vt, const unsigned char* __restrict__ BK,
    const float* __restrict__ TB, unsigned short* __restrict__ Y)
{
    __shared__ __align__(16) unsigned short sK[2][2][64][64];    // 32 KiB
    __shared__ __align__(16) unsigned short sV[2][2][128][64];   // 64 KiB
    __shared__ __align__(16) unsigned char  sBK[2][2][64][64];   // 16 KiB

    const int tid = threadIdx.x, wv = tid >> 6, lane = tid & 63;
    const int g = lane >> 4, lr = lane & 15;

    const int bid = blockIdx.x;
    const int xcd = bid & 7, kix = bid >> 3;
    const int bh = 2 * xcd + (kix & 1);
    const int ti = 31 - (kix >> 1);
    const int b = bh >> 3, h = bh & 7;
    const int i0 = ti * 64;
    const int rg = wv & 3;
    const int half = wv >> 2;
    const int irow = i0 + rg * 16;
    const int P = (ti + 2) >> 1;

    const int tbl = __float_as_int(TB[lane * 8 + h]);

    const unsigned short* qb = Q + ((size_t)bh << 11) * 64;
    const unsigned short* kb = K + ((size_t)bh << 11) * 64;
    const unsigned short* vtb = Vt + ((size_t)bh << 7) * 2048;
    const unsigned char* bkb = BK + ((size_t)b << 22);

    s16x8 aq[2];
    #pragma unroll
    for (int kq = 0; kq < 2; ++kq)
        aq[kq] = *reinterpret_cast<const s16x8*>(&qb[(size_t)(irow + lr) * 64 + kq * 32 + g * 8]);

    char* sKb = (char*)&sK[0][0][0][0];
    char* sVb = (char*)&sV[0][0][0][0];
    char* sBKb = (char*)&sBK[0][0][0][0];
    const int cs = lr & 7;
    const int ib = irow + lr;

    auto stage = [&](int q, int db) {
        int jth = 2 * q + half;
        if (jth > ti) jth = 2 * q;
        const size_t j0 = (size_t)jth * 64;
        char* kd = sKb + db * 16384 + half * 8192;
        char* vd = sVb + db * 32768 + half * 16384;
        char* bkd = sBKb + db * 8192 + half * 4096;
        #pragma unroll
        for (int c = 0; c < 2; ++c) {
            int chunk = rg * 128 + c * 64 + lane;
            int row = chunk >> 3, c8 = chunk & 7;
            GLDS16(kb + (j0 + row) * 64 + ((c8 ^ (row & 7)) * 8), kd + chunk * 16);
        }
        #pragma unroll
        for (int c = 0; c < 4; ++c) {
            int chunk = rg * 256 + c * 64 + lane;
            int d = chunk >> 3, c8 = chunk & 7;
            GLDS16(vtb + (size_t)d * 2048 + j0 + ((c8 ^ (d & 7)) * 8), vd + chunk * 16);
        }
        {
            int chunk = rg * 64 + lane;
            int row = chunk >> 2, c16 = chunk & 3;
            GLDS16(bkb + (size_t)(i0 + row) * 2048 + j0 + ((c16 ^ (row & 3)) * 16), bkd + chunk * 16);
        }
    };

    f32x4 accy[8] = {};

#define COMPUTE(DB) { \
        const int jt = 2 * p + half; \
        if (jt <= ti) { \
            const char* kbase = sKb + (DB) * 16384 + half * 8192; \
            f32x4 sacc[4] = {}; \
            _Pragma("unroll") \
            for (int ni = 0; ni < 4; ++ni) { \
                _Pragma("unroll") \
                for (int kq = 0; kq < 2; ++kq) { \
                    s16x8 kf = *reinterpret_cast<const s16x8*>( \
                        kbase + (ni * 16 + lr) * 128 + (((kq * 4 + g) ^ cs) << 4)); \
                    sacc[ni] = __builtin_amdgcn_mfma_f32_16x16x32_bf16(kf, aq[kq], sacc[ni], 0, 0, 0); \
                } \
            } \
            const int j0 = jt * 64; \
            const bool diag = (jt == ti); \
            s16x4 pf[4]; \
            _Pragma("unroll") \
            for (int ni = 0; ni < 4; ++ni) { \
                unsigned int bw = *reinterpret_cast<const unsigned int*>( \
                    sBKb + (DB) * 8192 + half * 4096 + (rg * 16 + lr) * 64 + ((ni ^ (lr & 3)) << 4) + g * 4); \
                float b0 = __int_as_float(__builtin_amdgcn_ds_bpermute((int)((bw & 255u) << 2), tbl)); \
                float b1 = __int_as_float(__builtin_amdgcn_ds_bpermute((int)(((bw >> 8) & 255u) << 2), tbl)); \
                float b2 = __int_as_float(__builtin_amdgcn_ds_bpermute((int)(((bw >> 16) & 255u) << 2), tbl)); \
                float b3 = __int_as_float(__builtin_amdgcn_ds_bpermute((int)((bw >> 24) << 2), tbl)); \
                float v0 = silu_fast(sacc[ni][0] + b0); \
                float v1 = silu_fast(sacc[ni][1] + b1); \
                float v2 = silu_fast(sacc[ni][2] + b2); \
                float v3 = silu_fast(sacc[ni][3] + b3); \
                if (diag) { \
                    int jb = j0 + ni * 16 + g * 4; \
                    if (jb + 0 > ib) v0 = 0.f; \
                    if (jb + 1 > ib) v1 = 0.f; \
                    if (jb + 2 > ib) v2 = 0.f; \
                    if (jb + 3 > ib) v3 = 0.f; \
                } \
                unsigned int w0, w1; \
                asm("v_cvt_pk_bf16_f32 %0, %1, %2" : "=v"(w0) : "v"(v0), "v"(v1)); \
                asm("v_cvt_pk_bf16_f32 %0, %1, %2" : "=v"(w1) : "v"(v2), "v"(v3)); \
                union { unsigned int u_[2]; s16x4 v_; } cvt_; \
                cvt_.u_[0] = w0; cvt_.u_[1] = w1; \
                pf[ni] = cvt_.v_; \
            } \
            const char* vbase = sVb + (DB) * 32768 + half * 16384; \
            _Pragma("unroll") \
            for (int di = 0; di < 8; ++di) { \
                _Pragma("unroll") \
                for (int ni = 0; ni < 4; ++ni) { \
                    s16x4 vf = *reinterpret_cast<const s16x4*>( \
                        vbase + (di * 16 + lr) * 128 + (((2 * ni + (g >> 1)) ^ cs) << 4) + ((g & 1) << 3)); \
                    accy[di] = __builtin_amdgcn_mfma_f32_16x16x16bf16_1k(pf[ni], vf, accy[di], 0, 0, 0); \
                } \
            } \
        } }

    stage(0, 0);

    int p = 0;
    for (;;) {
        __builtin_amdgcn_s_barrier();
        if (p + 1 < P) {
            stage(p + 1, 1);
            asm volatile("s_waitcnt vmcnt(7)" ::: "memory");
        } else {
            asm volatile("s_waitcnt vmcnt(0)" ::: "memory");
        }
        __builtin_amdgcn_s_barrier();
        COMPUTE(0);
        if (++p == P) break;
        __builtin_amdgcn_s_barrier();
        if (p + 1 < P) {
            stage(p + 1, 0);
            asm volatile("s_waitcnt vmcnt(7)" ::: "memory");
        } else {
            asm volatile("s_waitcnt vmcnt(0)" ::: "memory");
        }
        __builtin_amdgcn_s_barrier();
        COMPUTE(1);
        if (++p == P) break;
    }
#undef COMPUTE

    __syncthreads();
    float* red = (float*)sVb;
    if (wv >= 4) {
        #pragma unroll
        for (int di = 0; di < 8; ++di)
            #pragma unroll
            for (int r = 0; r < 4; ++r)
                red[(rg * 16 + g * 4 + r) * 132 + di * 16 + lr] = accy[di][r];
    }
    __syncthreads();
    if (wv < 4) {
        #pragma unroll
        for (int di = 0; di < 8; ++di)
            #pragma unroll
            for (int r = 0; r < 4; ++r) {
                float s = accy[di][r] + red[(rg * 16 + g * 4 + r) * 132 + di * 16 + lr];
                Y[(size_t)((b << 11) + irow + g * 4 + r) * 1024 + h * 128 + di * 16 + lr] = f2bf(s);
            }
    }
}

// ---------------------------------------------------------------------------
// Kernel 4: RMSNorm over HID=1024 then U-gate; Y bf16 in, bf16 YP out.
// ---------------------------------------------------------------------------
__global__ __launch_bounds__(256) void rmsnorm_gate(
    const unsigned short* __restrict__ Y, const unsigned short* __restrict__ U,
    const float* __restrict__ rw, unsigned short* __restrict__ YP)
{
    __shared__ float red[4];
    const int row = blockIdx.x, tid = threadIdx.x;
    u16x4 v4 = *reinterpret_cast<const u16x4*>(&Y[(size_t)row * 1024 + tid * 4]);
    float v[4];
    #pragma unroll
    for (int j = 0; j < 4; ++j) v[j] = bf2f(v4[j]);
    float ss = v[0] * v[0] + v[1] * v[1] + v[2] * v[2] + v[3] * v[3];
    #pragma unroll
    for (int off = 32; off; off >>= 1) ss += __shfl_down(ss, off);
    if ((tid & 63) == 0) red[tid >> 6] = ss;
    __syncthreads();
    float rms = rsqrtf((red[0] + red[1] + red[2] + red[3]) * (1.f / 1024.f) + 1e-6f);
    #pragma unroll
    for (int j = 0; j < 4; ++j) {
        int c = tid * 4 + j;
        float o = v[j] * rms * rw[c] * bf2f(U[(size_t)row * 1024 + c]);
        YP[(size_t)row * 1024 + c] = f2bf(o);
    }
}

// ---------------------------------------------------------------------------
// Kernel 5: OUT = YP @ Wob^T + b_o. (frozen at R10)
// ---------------------------------------------------------------------------
__global__ __launch_bounds__(512) void gemm_out(
    const unsigned short* __restrict__ YP, const unsigned short* __restrict__ Wob,
    const float* __restrict__ bo, float* __restrict__ OUT)
{
    __shared__ __align__(16) unsigned short sA[128][64];
    __shared__ __align__(16) unsigned short sB[128][64];
    const int tid = threadIdx.x;
    const int wv = tid >> 6, lane = tid & 63;
    const int g = lane >> 4, lr = lane & 15;
    const int wid = (blockIdx.x & 7) * 32 + (blockIdx.x >> 3);   // 256 blocks
    const int m0 = (wid & 31) * 128, n0 = (wid >> 5) * 128;
    const int wr = (wv >> 2) * 64, wc = (wv & 3) * 32;
    const int ls = lr & 7;
    f32x4 acc[4][2] = {};

    for (int k0 = 0; k0 < 1024; k0 += 64) {
        #pragma unroll
        for (int c = 0; c < 2; ++c) {
            int id = c * 512 + tid;
            int row = id >> 3, c8 = id & 7;
            int sc = (c8 ^ (row & 7)) * 8;
            GLDS16(&YP[(size_t)(m0 + row) * 1024 + k0 + sc], &sA[row][c8 * 8]);
            GLDS16(&Wob[(size_t)(n0 + row) * 1024 + k0 + sc], &sB[row][c8 * 8]);
        }
        __syncthreads();
        #pragma unroll
        for (int kq = 0; kq < 2; ++kq) {
            s16x8 afr[4], bfr[2];
            #pragma unroll
            for (int i = 0; i < 4; ++i)
                afr[i] = *reinterpret_cast<const s16x8*>(
                    &sA[wr + i * 16 + lr][((kq * 4 + g) ^ ls) * 8]);
            #pragma unroll
            for (int i = 0; i < 2; ++i)
                bfr[i] = *reinterpret_cast<const s16x8*>(
                    &sB[wc + i * 16 + lr][((kq * 4 + g) ^ ls) * 8]);
            #pragma unroll
            for (int mi = 0; mi < 4; ++mi)
                #pragma unroll
                for (int ni = 0; ni < 2; ++ni)
                    acc[mi][ni] = __builtin_amdgcn_mfma_f32_16x16x32_bf16(
                        afr[mi], bfr[ni], acc[mi][ni], 0, 0, 0);
        }
        __syncthreads();
    }

    #pragma unroll
    for (int ni = 0; ni < 2; ++ni) {
        int n = n0 + wc + ni * 16 + lr;
        float bn = bo[n];
        #pragma unroll
        for (int mi = 0; mi < 4; ++mi)
            #pragma unroll
            for (int r = 0; r < 4; ++r) {
                int m = m0 + wr + mi * 16 + g * 4 + r;
                OUT[(size_t)m * 1024 + n] = acc[mi][ni][r] + bn;
            }
    }
}

// ---------------------------------------------------------------------------
extern "C" void kernel_launch(void* const* d_in, const int* in_sizes, int n_in,
                              void* d_out, int out_size, void* d_ws, size_t ws_size,
                              hipStream_t stream) {
    const float* X     = (const float*)d_in[0];
    const int*   TS    = (const int*)d_in[1];
    // d_in[2] = attn_mask (causal) — recomputed on device
    const float* Wuvqk = (const float*)d_in[3];
    const float* buvqk = (const float*)d_in[4];
    const float* TB    = (const float*)d_in[5];
    const float* Wo    = (const float*)d_in[6];
    const float* bo    = (const float*)d_in[7];
    const float* rw    = (const float*)d_in[8];
    float* OUT = (float*)d_out;

    char* ws = (char*)d_ws;
    unsigned short* Qb  = (unsigned short*)(ws);               //  4 MiB [2][8][2048][64]
    unsigned short* Kb  = (unsigned short*)(ws + (4u << 20));  //  4 MiB
    unsigned short* Vt  = (unsigned short*)(ws + (8u << 20));  //  8 MiB [2][8][128][2048]
    unsigned short* Ub  = (unsigned short*)(ws + (16u << 20)); //  8 MiB [4096][1024]
    unsigned short* Yb  = (unsigned short*)(ws + (24u << 20)); //  8 MiB bf16 (aliases Xb)
    unsigned short* Xb  = (unsigned short*)(ws + (24u << 20)); //  8 MiB
    unsigned short* Wb  = (unsigned short*)(ws + (32u << 20)); //  6 MiB
    unsigned short* YP  = (unsigned short*)(ws + (40u << 20)); //  8 MiB [4096][1024]
    unsigned char*  BKm = (unsigned char*)(ws + (48u << 20));  //  8 MiB [2][2048][2048]
    unsigned short* Wob = (unsigned short*)(ws + (56u << 20)); //  2 MiB [1024][1024]

    cvt_bucketize<<<10240, 256, 0, stream>>>(X, Wuvqk, Wo, TS, Xb, Wb, Wob, BKm);
    gemm_uvqk<<<192, 512, 0, stream>>>(Xb, Wb, buvqk, Ub, Vt, Qb, Kb);
    attn<<<512, 512, 0, stream>>>(Qb, Kb, Vt, BKm, TB, Yb);
    rmsnorm_gate<<<4096, 256, 0, stream>>>(Yb, Ub, rw, YP);
    gemm_out<<<256, 512, 0, stream>>>(YP, Wob, bo, OUT);
}